// Round 5
// baseline (448.467 us; speedup 1.0000x reference)
//
#include <hip/hip_runtime.h>
#include <hip/hip_bf16.h>

#ifndef BN_EPS
#define BN_EPS 1e-5f
#endif

// ---------------------------------------------------------------------------
// N=100000, C=64, E=1600000.
// R5: replace gemm->stats->bn (3 passes over 25.6MB out, and gemm's 80MB
// partial-line store amplification) with two passes over the 12.8MB bf16 agg:
//   gemm1: o = agg@W, accumulate per-channel sum/sumsq in regs, NO stores.
//   bnprep: scale/shift from sums.
//   gemm2: recompute o, apply BN+ReLU, store once — lane=channel layout so
//          each row store is 256B contiguous (full lines, no amplification).
// Rest of pipeline unchanged from R4 (bucketed CSR build, paired-edge agg).
// bias cancels inside BatchNorm, skipped.
// ---------------------------------------------------------------------------

#define NPB 8192
#define NPB_SHIFT 13

__device__ __forceinline__ unsigned short f2bf(float f) {
    unsigned u = __float_as_uint(f);
    u += 0x7FFF + ((u >> 16) & 1);  // round-to-nearest-even
    return (unsigned short)(u >> 16);
}
__device__ __forceinline__ float bf2f(unsigned v) {
    return __uint_as_float(v << 16);
}

// deg count (int atomics) + x -> bf16 conversion, fused.
__global__ __launch_bounds__(256) void k_pre(const float* __restrict__ x,
                                             const int* __restrict__ dst,
                                             int* __restrict__ deg,
                                             unsigned short* __restrict__ xb,
                                             int E, int n4) {
    int i = blockIdx.x * 256 + threadIdx.x;
    if (i < E) atomicAdd(&deg[dst[i]], 1);
    if (i < n4) {
        float4 v = ((const float4*)x)[i];
        ushort4 b;
        b.x = f2bf(v.x); b.y = f2bf(v.y); b.z = f2bf(v.z); b.w = f2bf(v.w);
        ((ushort4*)xb)[i] = b;
    }
}

// ---- exclusive scan of deg[N] -> offs/cur, fused dinv + bucket bases -------
__global__ __launch_bounds__(256) void k_scan1(const int* __restrict__ deg,
                                               int* __restrict__ part, int N) {
    __shared__ int s[256];
    int tid = threadIdx.x;
    int i = blockIdx.x * 256 + tid;
    s[tid] = (i < N) ? deg[i] : 0;
    __syncthreads();
    for (int off = 128; off > 0; off >>= 1) {
        if (tid < off) s[tid] += s[tid + off];
        __syncthreads();
    }
    if (tid == 0) part[blockIdx.x] = s[0];
}

__global__ __launch_bounds__(512) void k_scan2(const int* __restrict__ part,
                                               int* __restrict__ base, int NB) {
    __shared__ int s[512];
    int t = threadIdx.x;
    int v = (t < NB) ? part[t] : 0;
    s[t] = v;
    __syncthreads();
    for (int off = 1; off < 512; off <<= 1) {
        int add = (t >= off) ? s[t - off] : 0;
        __syncthreads();
        s[t] += add;
        __syncthreads();
    }
    if (t < NB) base[t] = s[t] - v;  // exclusive
}

__global__ __launch_bounds__(256) void k_scan3(const int* __restrict__ deg,
                                               const int* __restrict__ base,
                                               int* __restrict__ offs,
                                               int* __restrict__ cur,
                                               float* __restrict__ dinv,
                                               int* __restrict__ bbase,
                                               int* __restrict__ bcur, int N) {
    __shared__ int s[256];
    int tid = threadIdx.x;
    int i = blockIdx.x * 256 + tid;
    int v = (i < N) ? deg[i] : 0;
    s[tid] = v;
    __syncthreads();
    for (int off = 1; off < 256; off <<= 1) {
        int add = (tid >= off) ? s[tid - off] : 0;
        __syncthreads();
        s[tid] += add;
        __syncthreads();
    }
    if (i < N) {
        int excl = s[tid] - v + base[blockIdx.x];
        offs[i] = excl;
        cur[i] = excl;
        dinv[i] = rsqrtf((float)(v + 1));  // +1 = self-loop
        if ((i & (NPB - 1)) == 0) {
            bbase[i >> NPB_SHIFT] = excl;
            bcur[i >> NPB_SHIFT] = excl;
        }
    }
}

// Chunked 13-bucket counting sort: binned[] filled in coalesced runs.
// packed entry = src (bits 0-16) | local_dst (bits 17-29).
__global__ __launch_bounds__(256) void k_bin(const int* __restrict__ src,
                                             const int* __restrict__ dst,
                                             int* __restrict__ bcur,
                                             unsigned* __restrict__ binned, int E) {
    __shared__ int hist[16];
    __shared__ int hexcl[16];
    __shared__ int hcur[16];
    __shared__ int gbase[16];
    __shared__ unsigned lout[4096];
    __shared__ unsigned char lb[4096];
    int tid = threadIdx.x;
    int c0 = blockIdx.x * 4096;
    int cnt = min(4096, E - c0);
    if (tid < 16) hist[tid] = 0;
    __syncthreads();
    for (int i = tid; i < cnt; i += 256) {
        int b = dst[c0 + i] >> NPB_SHIFT;
        atomicAdd(&hist[b], 1);
    }
    __syncthreads();
    if (tid == 0) {
        int acc = 0;
        for (int b = 0; b < 16; b++) { hexcl[b] = acc; hcur[b] = acc; acc += hist[b]; }
    }
    __syncthreads();
    if (tid < 16 && hist[tid] > 0) gbase[tid] = atomicAdd(&bcur[tid], hist[tid]);
    for (int i = tid; i < cnt; i += 256) {
        int d = dst[c0 + i];
        int s = src[c0 + i];
        int b = d >> NPB_SHIFT;
        unsigned packed = (unsigned)s | ((unsigned)(d & (NPB - 1)) << 17);
        int p = atomicAdd(&hcur[b], 1);
        lout[p] = packed;
        lb[p] = (unsigned char)b;
    }
    __syncthreads();
    for (int i = tid; i < cnt; i += 256) {
        int b = lb[i];
        binned[gbase[b] + (i - hexcl[b])] = lout[i];
    }
}

// Per-bucket local fill. Bucket b handled by blocks with blockIdx%8 == b%8
// (round-robin XCD heuristic): csr window (512KB) stays in one XCD's L2.
__global__ __launch_bounds__(256) void k_fillL(const unsigned* __restrict__ binned,
                                               const int* __restrict__ bbase,
                                               int* __restrict__ cur,
                                               int* __restrict__ csr, int E, int B) {
    int x = blockIdx.x & 7;   // presumed XCD
    int r = blockIdx.x >> 3;  // rank within XCD, 0..31
    for (int b = x; b < B; b += 8) {
        int bs = bbase[b];
        int be = (b + 1 < B) ? bbase[b + 1] : E;
        int base_node = b << NPB_SHIFT;
        for (int j = bs + r * 256 + threadIdx.x; j < be; j += 32 * 256) {
            unsigned e = binned[j];
            int s = (int)(e & 0x1FFFFu);
            int node = base_node + (int)(e >> 17);
            int pos = atomicAdd(&cur[node], 1);
            csr[pos] = s;
        }
    }
}

// Wave per node. lane = (half h, channel-pair p): one 4B load = 2 channels of
// one of 2 edges -> 2 edges per load instruction. Halves combined at the end.
__global__ __launch_bounds__(256) void k_agg(const int* __restrict__ offs,
                                             const int* __restrict__ cur,
                                             const int* __restrict__ csr,
                                             const unsigned short* __restrict__ xb,
                                             const float* __restrict__ dinv,
                                             unsigned* __restrict__ aggb32, int N) {
    int lane = threadIdx.x & 63;
    int p = lane & 31;   // channel pair (channels 2p, 2p+1)
    int h = lane >> 5;   // half: which edge of a pair this lane gathers
    int wid = (blockIdx.x * 256 + threadIdx.x) >> 6;
    int nw = (gridDim.x * 256) >> 6;

    for (int n = wid; n < N; n += nw) {
        float dn = dinv[n];
        unsigned sv = *(const unsigned*)(xb + (size_t)n * 64 + 2 * p);
        float wself = (h == 0) ? dn : 0.f;  // self-loop counted once
        float accx = bf2f(sv & 0xFFFFu) * wself;
        float accy = bf2f(sv >> 16) * wself;
        int j0 = offs[n];
        int j1 = cur[n];  // == offs[n] + deg[n]
        for (int jb = j0; jb < j1; jb += 64) {
            int cnt = min(64, j1 - jb);
            int idx = 0;
            float w = 0.f;
            if (lane < cnt) {
                idx = csr[jb + lane];
                w = dinv[idx];
            }
            int j = 0;
            for (; j + 8 <= cnt; j += 8) {
                int s0 = __shfl(idx, j + 0 + h), s1 = __shfl(idx, j + 2 + h);
                int s2 = __shfl(idx, j + 4 + h), s3 = __shfl(idx, j + 6 + h);
                float w0 = __shfl(w, j + 0 + h), w1 = __shfl(w, j + 2 + h);
                float w2 = __shfl(w, j + 4 + h), w3 = __shfl(w, j + 6 + h);
                unsigned v0 = *(const unsigned*)(xb + (size_t)s0 * 64 + 2 * p);
                unsigned v1 = *(const unsigned*)(xb + (size_t)s1 * 64 + 2 * p);
                unsigned v2 = *(const unsigned*)(xb + (size_t)s2 * 64 + 2 * p);
                unsigned v3 = *(const unsigned*)(xb + (size_t)s3 * 64 + 2 * p);
                accx = fmaf(w0, bf2f(v0 & 0xFFFFu), accx);
                accy = fmaf(w0, bf2f(v0 >> 16), accy);
                accx = fmaf(w1, bf2f(v1 & 0xFFFFu), accx);
                accy = fmaf(w1, bf2f(v1 >> 16), accy);
                accx = fmaf(w2, bf2f(v2 & 0xFFFFu), accx);
                accy = fmaf(w2, bf2f(v2 >> 16), accy);
                accx = fmaf(w3, bf2f(v3 & 0xFFFFu), accx);
                accy = fmaf(w3, bf2f(v3 >> 16), accy);
            }
            for (; j + 2 <= cnt; j += 2) {
                int s0 = __shfl(idx, j + h);
                float w0 = __shfl(w, j + h);
                unsigned v0 = *(const unsigned*)(xb + (size_t)s0 * 64 + 2 * p);
                accx = fmaf(w0, bf2f(v0 & 0xFFFFu), accx);
                accy = fmaf(w0, bf2f(v0 >> 16), accy);
            }
            if (j < cnt) {  // odd tail: half 0 contributes, half 1 gets w=0
                int s0 = __shfl(idx, j);
                float w0 = __shfl(w, j);
                if (h) w0 = 0.f;
                unsigned v0 = *(const unsigned*)(xb + (size_t)s0 * 64 + 2 * p);
                accx = fmaf(w0, bf2f(v0 & 0xFFFFu), accx);
                accy = fmaf(w0, bf2f(v0 >> 16), accy);
            }
        }
        accx += __shfl_xor(accx, 32);
        accy += __shfl_xor(accy, 32);
        if (h == 0) {
            unsigned o = (unsigned)f2bf(accx * dn) | ((unsigned)f2bf(accy * dn) << 16);
            aggb32[(size_t)n * 32 + p] = o;
        }
    }
}

// Pass 1: o = agg@W per row (lane=channel, W column in 64 regs, row value
// broadcast via shfl). Accumulate per-channel sum/sumsq; NO global stores.
__global__ __launch_bounds__(256) void k_gemm1(const unsigned short* __restrict__ aggb,
                                               const float* __restrict__ W,
                                               float* __restrict__ stats, int N) {
    int lane = threadIdx.x & 63;
    float wcol[64];
#pragma unroll
    for (int k = 0; k < 64; k++) wcol[k] = W[k * 64 + lane];

    int wid = (blockIdx.x * 256 + threadIdx.x) >> 6;
    int nw = (gridDim.x * 256) >> 6;
    float psum = 0.f, psq = 0.f;

    int n = wid * 2;
    for (; n + 1 < N; n += nw * 2) {
        float a0 = bf2f(aggb[(size_t)n * 64 + lane]);
        float a1 = bf2f(aggb[(size_t)(n + 1) * 64 + lane]);
        float acc0 = 0.f, acc1 = 0.f;
#pragma unroll
        for (int k = 0; k < 64; k++) {
            acc0 = fmaf(__shfl(a0, k), wcol[k], acc0);
            acc1 = fmaf(__shfl(a1, k), wcol[k], acc1);
        }
        psum += acc0 + acc1;
        psq = fmaf(acc0, acc0, psq);
        psq = fmaf(acc1, acc1, psq);
    }
    if (n < N) {
        float a0 = bf2f(aggb[(size_t)n * 64 + lane]);
        float acc0 = 0.f;
#pragma unroll
        for (int k = 0; k < 64; k++) acc0 = fmaf(__shfl(a0, k), wcol[k], acc0);
        psum += acc0;
        psq = fmaf(acc0, acc0, psq);
    }
    atomicAdd(&stats[lane], psum);
    atomicAdd(&stats[64 + lane], psq);
}

__global__ void k_bnprep(const float* __restrict__ stats,
                         const float* __restrict__ gamma,
                         const float* __restrict__ beta,
                         float* __restrict__ ss, float invN) {
    int c = threadIdx.x;  // 64 threads
    float mean = stats[c] * invN;
    float var = stats[64 + c] * invN - mean * mean;  // biased var
    float scale = gamma[c] * rsqrtf(var + BN_EPS);
    ss[c] = scale;
    ss[64 + c] = beta[c] - mean * scale;
}

// Pass 2: recompute o, apply BN+ReLU, store. Per-row store = 64 lanes x 4B
// = 256B contiguous (full 64B lines only -> no write amplification).
__global__ __launch_bounds__(256) void k_gemm2(const unsigned short* __restrict__ aggb,
                                               const float* __restrict__ W,
                                               const float* __restrict__ ss,
                                               float* __restrict__ out, int N) {
    int lane = threadIdx.x & 63;
    float wcol[64];
#pragma unroll
    for (int k = 0; k < 64; k++) wcol[k] = W[k * 64 + lane];
    float sc = ss[lane];
    float sh = ss[64 + lane];

    int wid = (blockIdx.x * 256 + threadIdx.x) >> 6;
    int nw = (gridDim.x * 256) >> 6;

    int n = wid * 2;
    for (; n + 1 < N; n += nw * 2) {
        float a0 = bf2f(aggb[(size_t)n * 64 + lane]);
        float a1 = bf2f(aggb[(size_t)(n + 1) * 64 + lane]);
        float acc0 = 0.f, acc1 = 0.f;
#pragma unroll
        for (int k = 0; k < 64; k++) {
            acc0 = fmaf(__shfl(a0, k), wcol[k], acc0);
            acc1 = fmaf(__shfl(a1, k), wcol[k], acc1);
        }
        out[(size_t)n * 64 + lane] = fmaxf(fmaf(acc0, sc, sh), 0.f);
        out[(size_t)(n + 1) * 64 + lane] = fmaxf(fmaf(acc1, sc, sh), 0.f);
    }
    if (n < N) {
        float a0 = bf2f(aggb[(size_t)n * 64 + lane]);
        float acc0 = 0.f;
#pragma unroll
        for (int k = 0; k < 64; k++) acc0 = fmaf(__shfl(a0, k), wcol[k], acc0);
        out[(size_t)n * 64 + lane] = fmaxf(fmaf(acc0, sc, sh), 0.f);
    }
}

extern "C" void kernel_launch(void* const* d_in, const int* in_sizes, int n_in,
                              void* d_out, int out_size, void* d_ws, size_t ws_size,
                              hipStream_t stream) {
    const float* x = (const float*)d_in[0];
    const int* ei = (const int*)d_in[1];
    const float* W = (const float*)d_in[2];
    // d_in[3] = bias: cancels inside BatchNorm, unused.
    const float* gamma = (const float*)d_in[4];
    const float* beta = (const float*)d_in[5];
    float* out = (float*)d_out;

    const int N = in_sizes[0] / 64;
    const int E = in_sizes[1] / 2;
    const int* src = ei;
    const int* dst = ei + E;
    const int NB = (N + 255) / 256;            // 391 (<=512 for k_scan2)
    const int B = (N + NPB - 1) >> NPB_SHIFT;  // 13 buckets

    char* ws = (char*)d_ws;
    int* deg = (int*)ws;                                    // 4N
    float* stats = (float*)(ws + (size_t)4 * N);            // 512 B
    float* ss = (float*)(ws + (size_t)4 * N + 512);         // 512 B
    int* part = (int*)(ws + (size_t)4 * N + 1024);          // 2 KB
    int* base = (int*)(ws + (size_t)4 * N + 3072);          // 2 KB
    int* bbase = (int*)(ws + (size_t)4 * N + 5120);         // 64 B
    int* bcur = (int*)(ws + (size_t)4 * N + 5184);          // 64 B
    int* offs = (int*)(ws + (size_t)4 * N + 5376);          // 4N
    int* cur = (int*)(ws + (size_t)8 * N + 5376);           // 4N
    float* dinv = (float*)(ws + (size_t)12 * N + 5376);     // 4N
    unsigned short* xb = (unsigned short*)(ws + (size_t)16 * N + 5376);   // 128N
    unsigned short* aggb = (unsigned short*)(ws + (size_t)144 * N + 5376);// 128N
    unsigned* binned = (unsigned*)(ws + (size_t)272 * N + 5376);          // 4E
    int* csr = (int*)(ws + (size_t)272 * N + (size_t)4 * E + 5376);       // 4E

    // zero deg + stats (contiguous)
    hipMemsetAsync(deg, 0, (size_t)4 * N + 512, stream);

    int n4 = N * 16;
    int preN = (E > n4) ? E : n4;
    k_pre<<<(preN + 255) / 256, 256, 0, stream>>>(x, dst, deg, xb, E, n4);
    k_scan1<<<NB, 256, 0, stream>>>(deg, part, N);
    k_scan2<<<1, 512, 0, stream>>>(part, base, NB);
    k_scan3<<<NB, 256, 0, stream>>>(deg, base, offs, cur, dinv, bbase, bcur, N);
    k_bin<<<(E + 4095) / 4096, 256, 0, stream>>>(src, dst, bcur, binned, E);
    k_fillL<<<256, 256, 0, stream>>>(binned, bbase, cur, csr, E, B);
    k_agg<<<2048, 256, 0, stream>>>(offs, cur, csr, xb, dinv, (unsigned*)aggb, N);
    k_gemm1<<<512, 256, 0, stream>>>(aggb, W, stats, N);
    k_bnprep<<<1, 64, 0, stream>>>(stats, gamma, beta, ss, 1.0f / (float)N);
    k_gemm2<<<512, 256, 0, stream>>>(aggb, W, ss, out, N);
}

// Round 6
// 397.474 us; speedup vs baseline: 1.1283x; 1.1283x over previous
//
#include <hip/hip_runtime.h>
#include <hip/hip_bf16.h>

#ifndef BN_EPS
#define BN_EPS 1e-5f
#endif

// ---------------------------------------------------------------------------
// N=100000, C=64, E=1600000.
// R6: R4 pipeline + amplification-free, shfl-free tail:
//   k_moment: M = agg^T agg (64x64) + rowsum s, LDS-tiled, reg-blocked 4x4.
//   k_bnprep2: mean = s@W/N; E[o^2]_c = w_c^T M w_c / N; -> scale/shift.
//   k_gemm2: lane=channel GEMM (agg rows staged in LDS, broadcast reads;
//            W column in 64 VGPRs) + BN + ReLU; store = 1 dword/lane =
//            256B contiguous per row -> full 64B lines, no amplification.
// (R5 lesson: __shfl = ds_bpermute ~6cyc via LDS pipe; 64/row was latency
//  death. R4 lesson: 16B/lane scattered stores amplify 3.1x at writeback.)
// bias cancels inside BatchNorm, skipped.
// ---------------------------------------------------------------------------

#define NPB 8192
#define NPB_SHIFT 13

__device__ __forceinline__ unsigned short f2bf(float f) {
    unsigned u = __float_as_uint(f);
    u += 0x7FFF + ((u >> 16) & 1);  // round-to-nearest-even
    return (unsigned short)(u >> 16);
}
__device__ __forceinline__ float bf2f(unsigned v) {
    return __uint_as_float(v << 16);
}

// deg count (int atomics) + x -> bf16 conversion, fused.
__global__ __launch_bounds__(256) void k_pre(const float* __restrict__ x,
                                             const int* __restrict__ dst,
                                             int* __restrict__ deg,
                                             unsigned short* __restrict__ xb,
                                             int E, int n4) {
    int i = blockIdx.x * 256 + threadIdx.x;
    if (i < E) atomicAdd(&deg[dst[i]], 1);
    if (i < n4) {
        float4 v = ((const float4*)x)[i];
        ushort4 b;
        b.x = f2bf(v.x); b.y = f2bf(v.y); b.z = f2bf(v.z); b.w = f2bf(v.w);
        ((ushort4*)xb)[i] = b;
    }
}

// ---- exclusive scan of deg[N] -> offs/cur, fused dinv + bucket bases -------
__global__ __launch_bounds__(256) void k_scan1(const int* __restrict__ deg,
                                               int* __restrict__ part, int N) {
    __shared__ int s[256];
    int tid = threadIdx.x;
    int i = blockIdx.x * 256 + tid;
    s[tid] = (i < N) ? deg[i] : 0;
    __syncthreads();
    for (int off = 128; off > 0; off >>= 1) {
        if (tid < off) s[tid] += s[tid + off];
        __syncthreads();
    }
    if (tid == 0) part[blockIdx.x] = s[0];
}

__global__ __launch_bounds__(512) void k_scan2(const int* __restrict__ part,
                                               int* __restrict__ base, int NB) {
    __shared__ int s[512];
    int t = threadIdx.x;
    int v = (t < NB) ? part[t] : 0;
    s[t] = v;
    __syncthreads();
    for (int off = 1; off < 512; off <<= 1) {
        int add = (t >= off) ? s[t - off] : 0;
        __syncthreads();
        s[t] += add;
        __syncthreads();
    }
    if (t < NB) base[t] = s[t] - v;  // exclusive
}

__global__ __launch_bounds__(256) void k_scan3(const int* __restrict__ deg,
                                               const int* __restrict__ base,
                                               int* __restrict__ offs,
                                               int* __restrict__ cur,
                                               float* __restrict__ dinv,
                                               int* __restrict__ bbase,
                                               int* __restrict__ bcur, int N) {
    __shared__ int s[256];
    int tid = threadIdx.x;
    int i = blockIdx.x * 256 + tid;
    int v = (i < N) ? deg[i] : 0;
    s[tid] = v;
    __syncthreads();
    for (int off = 1; off < 256; off <<= 1) {
        int add = (tid >= off) ? s[tid - off] : 0;
        __syncthreads();
        s[tid] += add;
        __syncthreads();
    }
    if (i < N) {
        int excl = s[tid] - v + base[blockIdx.x];
        offs[i] = excl;
        cur[i] = excl;
        dinv[i] = rsqrtf((float)(v + 1));  // +1 = self-loop
        if ((i & (NPB - 1)) == 0) {
            bbase[i >> NPB_SHIFT] = excl;
            bcur[i >> NPB_SHIFT] = excl;
        }
    }
}

// Chunked 13-bucket counting sort: binned[] filled in coalesced runs.
// packed entry = src (bits 0-16) | local_dst (bits 17-29).
__global__ __launch_bounds__(256) void k_bin(const int* __restrict__ src,
                                             const int* __restrict__ dst,
                                             int* __restrict__ bcur,
                                             unsigned* __restrict__ binned, int E) {
    __shared__ int hist[16];
    __shared__ int hexcl[16];
    __shared__ int hcur[16];
    __shared__ int gbase[16];
    __shared__ unsigned lout[4096];
    __shared__ unsigned char lb[4096];
    int tid = threadIdx.x;
    int c0 = blockIdx.x * 4096;
    int cnt = min(4096, E - c0);
    if (tid < 16) hist[tid] = 0;
    __syncthreads();
    for (int i = tid; i < cnt; i += 256) {
        int b = dst[c0 + i] >> NPB_SHIFT;
        atomicAdd(&hist[b], 1);
    }
    __syncthreads();
    if (tid == 0) {
        int acc = 0;
        for (int b = 0; b < 16; b++) { hexcl[b] = acc; hcur[b] = acc; acc += hist[b]; }
    }
    __syncthreads();
    if (tid < 16 && hist[tid] > 0) gbase[tid] = atomicAdd(&bcur[tid], hist[tid]);
    for (int i = tid; i < cnt; i += 256) {
        int d = dst[c0 + i];
        int s = src[c0 + i];
        int b = d >> NPB_SHIFT;
        unsigned packed = (unsigned)s | ((unsigned)(d & (NPB - 1)) << 17);
        int p = atomicAdd(&hcur[b], 1);
        lout[p] = packed;
        lb[p] = (unsigned char)b;
    }
    __syncthreads();
    for (int i = tid; i < cnt; i += 256) {
        int b = lb[i];
        binned[gbase[b] + (i - hexcl[b])] = lout[i];
    }
}

// Per-bucket local fill. Bucket b handled by blocks with blockIdx%8 == b%8
// (round-robin XCD heuristic): csr window (512KB) stays in one XCD's L2.
__global__ __launch_bounds__(256) void k_fillL(const unsigned* __restrict__ binned,
                                               const int* __restrict__ bbase,
                                               int* __restrict__ cur,
                                               int* __restrict__ csr, int E, int B) {
    int x = blockIdx.x & 7;   // presumed XCD
    int r = blockIdx.x >> 3;  // rank within XCD, 0..31
    for (int b = x; b < B; b += 8) {
        int bs = bbase[b];
        int be = (b + 1 < B) ? bbase[b + 1] : E;
        int base_node = b << NPB_SHIFT;
        for (int j = bs + r * 256 + threadIdx.x; j < be; j += 32 * 256) {
            unsigned e = binned[j];
            int s = (int)(e & 0x1FFFFu);
            int node = base_node + (int)(e >> 17);
            int pos = atomicAdd(&cur[node], 1);
            csr[pos] = s;
        }
    }
}

// Wave per node. lane = (half h, channel-pair p): one 4B load = 2 channels of
// one of 2 edges -> 2 edges per load instruction. Halves combined at the end.
__global__ __launch_bounds__(256) void k_agg(const int* __restrict__ offs,
                                             const int* __restrict__ cur,
                                             const int* __restrict__ csr,
                                             const unsigned short* __restrict__ xb,
                                             const float* __restrict__ dinv,
                                             unsigned* __restrict__ aggb32, int N) {
    int lane = threadIdx.x & 63;
    int p = lane & 31;   // channel pair (channels 2p, 2p+1)
    int h = lane >> 5;   // half: which edge of a pair this lane gathers
    int wid = (blockIdx.x * 256 + threadIdx.x) >> 6;
    int nw = (gridDim.x * 256) >> 6;

    for (int n = wid; n < N; n += nw) {
        float dn = dinv[n];
        unsigned sv = *(const unsigned*)(xb + (size_t)n * 64 + 2 * p);
        float wself = (h == 0) ? dn : 0.f;  // self-loop counted once
        float accx = bf2f(sv & 0xFFFFu) * wself;
        float accy = bf2f(sv >> 16) * wself;
        int j0 = offs[n];
        int j1 = cur[n];  // == offs[n] + deg[n]
        for (int jb = j0; jb < j1; jb += 64) {
            int cnt = min(64, j1 - jb);
            int idx = 0;
            float w = 0.f;
            if (lane < cnt) {
                idx = csr[jb + lane];
                w = dinv[idx];
            }
            int j = 0;
            for (; j + 8 <= cnt; j += 8) {
                int s0 = __shfl(idx, j + 0 + h), s1 = __shfl(idx, j + 2 + h);
                int s2 = __shfl(idx, j + 4 + h), s3 = __shfl(idx, j + 6 + h);
                float w0 = __shfl(w, j + 0 + h), w1 = __shfl(w, j + 2 + h);
                float w2 = __shfl(w, j + 4 + h), w3 = __shfl(w, j + 6 + h);
                unsigned v0 = *(const unsigned*)(xb + (size_t)s0 * 64 + 2 * p);
                unsigned v1 = *(const unsigned*)(xb + (size_t)s1 * 64 + 2 * p);
                unsigned v2 = *(const unsigned*)(xb + (size_t)s2 * 64 + 2 * p);
                unsigned v3 = *(const unsigned*)(xb + (size_t)s3 * 64 + 2 * p);
                accx = fmaf(w0, bf2f(v0 & 0xFFFFu), accx);
                accy = fmaf(w0, bf2f(v0 >> 16), accy);
                accx = fmaf(w1, bf2f(v1 & 0xFFFFu), accx);
                accy = fmaf(w1, bf2f(v1 >> 16), accy);
                accx = fmaf(w2, bf2f(v2 & 0xFFFFu), accx);
                accy = fmaf(w2, bf2f(v2 >> 16), accy);
                accx = fmaf(w3, bf2f(v3 & 0xFFFFu), accx);
                accy = fmaf(w3, bf2f(v3 >> 16), accy);
            }
            for (; j + 2 <= cnt; j += 2) {
                int s0 = __shfl(idx, j + h);
                float w0 = __shfl(w, j + h);
                unsigned v0 = *(const unsigned*)(xb + (size_t)s0 * 64 + 2 * p);
                accx = fmaf(w0, bf2f(v0 & 0xFFFFu), accx);
                accy = fmaf(w0, bf2f(v0 >> 16), accy);
            }
            if (j < cnt) {  // odd tail: half 0 contributes, half 1 gets w=0
                int s0 = __shfl(idx, j);
                float w0 = __shfl(w, j);
                if (h) w0 = 0.f;
                unsigned v0 = *(const unsigned*)(xb + (size_t)s0 * 64 + 2 * p);
                accx = fmaf(w0, bf2f(v0 & 0xFFFFu), accx);
                accy = fmaf(w0, bf2f(v0 >> 16), accy);
            }
        }
        accx += __shfl_xor(accx, 32);
        accy += __shfl_xor(accy, 32);
        if (h == 0) {
            unsigned o = (unsigned)f2bf(accx * dn) | ((unsigned)f2bf(accy * dn) << 16);
            aggb32[(size_t)n * 32 + p] = o;
        }
    }
}

// M = agg^T agg (64x64) + rowsum s. LDS-tiled 64 rows, thread owns 4x4 block
// (ti=t>>4 -> i-base 4ti, tj=t&15 -> j-base 4tj). 2 b128 reads + 16 fma / row.
__global__ __launch_bounds__(256) void k_moment(const unsigned* __restrict__ aggb32,
                                                float* __restrict__ M,
                                                float* __restrict__ s, int N) {
    __shared__ float tile[64 * 68];
    int t = threadIdx.x;
    int ti = t >> 4, tj = t & 15;
    float acc[4][4] = {{0.f}};
    float ssum[4] = {0.f, 0.f, 0.f, 0.f};
    int nt = (N + 63) >> 6;
    for (int tl = blockIdx.x; tl < nt; tl += gridDim.x) {
        int n0 = tl << 6;
        __syncthreads();
#pragma unroll
        for (int i = 0; i < 8; i++) {
            int idx = t + 256 * i;      // 0..2047
            int row = idx >> 5, p = idx & 31;
            int n = n0 + row;
            unsigned v = (n < N) ? aggb32[(size_t)n * 32 + p] : 0u;
            float2 f;
            f.x = bf2f(v & 0xFFFFu);
            f.y = bf2f(v >> 16);
            *(float2*)(tile + row * 68 + 2 * p) = f;
        }
        __syncthreads();
        for (int r = 0; r < 64; r++) {
            float4 ai = *(const float4*)(tile + r * 68 + 4 * ti);
            float4 aj = *(const float4*)(tile + r * 68 + 4 * tj);
            acc[0][0] = fmaf(ai.x, aj.x, acc[0][0]);
            acc[0][1] = fmaf(ai.x, aj.y, acc[0][1]);
            acc[0][2] = fmaf(ai.x, aj.z, acc[0][2]);
            acc[0][3] = fmaf(ai.x, aj.w, acc[0][3]);
            acc[1][0] = fmaf(ai.y, aj.x, acc[1][0]);
            acc[1][1] = fmaf(ai.y, aj.y, acc[1][1]);
            acc[1][2] = fmaf(ai.y, aj.z, acc[1][2]);
            acc[1][3] = fmaf(ai.y, aj.w, acc[1][3]);
            acc[2][0] = fmaf(ai.z, aj.x, acc[2][0]);
            acc[2][1] = fmaf(ai.z, aj.y, acc[2][1]);
            acc[2][2] = fmaf(ai.z, aj.z, acc[2][2]);
            acc[2][3] = fmaf(ai.z, aj.w, acc[2][3]);
            acc[3][0] = fmaf(ai.w, aj.x, acc[3][0]);
            acc[3][1] = fmaf(ai.w, aj.y, acc[3][1]);
            acc[3][2] = fmaf(ai.w, aj.z, acc[3][2]);
            acc[3][3] = fmaf(ai.w, aj.w, acc[3][3]);
            ssum[0] += ai.x; ssum[1] += ai.y; ssum[2] += ai.z; ssum[3] += ai.w;
        }
    }
#pragma unroll
    for (int a = 0; a < 4; a++)
#pragma unroll
        for (int b = 0; b < 4; b++)
            atomicAdd(&M[(4 * ti + a) * 64 + 4 * tj + b], acc[a][b]);
    if (tj == 0) {
#pragma unroll
        for (int a = 0; a < 4; a++) atomicAdd(&s[4 * ti + a], ssum[a]);
    }
}

// scale/shift from moments: mean_c = (s@W_c)/N; E[o^2]_c = (W_c^T M W_c)/N.
// 256 threads = 64 channels x 4 quarters of the i-range.
__global__ __launch_bounds__(256) void k_bnprep2(const float* __restrict__ M,
                                                 const float* __restrict__ s,
                                                 const float* __restrict__ W,
                                                 const float* __restrict__ gamma,
                                                 const float* __restrict__ beta,
                                                 float* __restrict__ ss, float invN) {
    __shared__ float red[256];
    int c = threadIdx.x & 63, q = threadIdx.x >> 6;
    float wc[64];
#pragma unroll
    for (int k = 0; k < 64; k++) wc[k] = W[k * 64 + c];
    float e2p = 0.f;
    for (int i = 16 * q; i < 16 * q + 16; i++) {
        float acc = 0.f;
#pragma unroll
        for (int k = 0; k < 64; k++) acc = fmaf(M[i * 64 + k], wc[k], acc);
        e2p = fmaf(wc[i], acc, e2p);
    }
    red[threadIdx.x] = e2p;
    __syncthreads();
    if (q == 0) {
        float e2 = (red[c] + red[64 + c] + red[128 + c] + red[192 + c]) * invN;
        float mean = 0.f;
#pragma unroll
        for (int k = 0; k < 64; k++) mean = fmaf(s[k], wc[k], mean);
        mean *= invN;
        float var = e2 - mean * mean;  // biased var, matches ref
        float scale = gamma[c] * rsqrtf(var + BN_EPS);
        ss[c] = scale;
        ss[64 + c] = beta[c] - mean * scale;
    }
}

// out = BN(agg@W)+ReLU. lane=channel: W column in 64 VGPRs; agg rows staged
// in LDS (raw bf16 pairs, broadcast reads). Store = 1 dword/lane = 256B
// contiguous per row (full 64B lines, no write amplification).
__global__ __launch_bounds__(256) void k_gemm2(const unsigned* __restrict__ aggb32,
                                               const float* __restrict__ W,
                                               const float* __restrict__ ss,
                                               float* __restrict__ out, int N) {
    __shared__ unsigned tile[256 * 32];  // 32 KB: 256 rows x 64 bf16
    int t = threadIdx.x;
    int lane = t & 63;
    int w = t >> 6;
    int r0 = blockIdx.x * 256;
    const uint4* gp = (const uint4*)(aggb32 + (size_t)r0 * 32);
#pragma unroll
    for (int i = 0; i < 8; i++) {
        int idx = t + 256 * i;  // uint4 index; row = idx>>3
        int n = r0 + (idx >> 3);
        uint4 v = {0u, 0u, 0u, 0u};
        if (n < N) v = gp[idx];
        *(uint4*)(tile + idx * 4) = v;
    }
    float wcol[64];
#pragma unroll
    for (int k = 0; k < 64; k++) wcol[k] = W[k * 64 + lane];
    float sc = ss[lane], sh = ss[64 + lane];
    __syncthreads();

    for (int rr = 0; rr < 64; rr += 2) {  // wave w: local rows 64w..64w+63
        int lr0 = w * 64 + rr;
        int n0 = r0 + lr0;
        if (n0 >= N) break;
        const unsigned* row0 = tile + lr0 * 32;
        const unsigned* row1 = row0 + 32;
        float o0 = 0.f, o1 = 0.f;
#pragma unroll
        for (int kp = 0; kp < 32; kp++) {
            unsigned u0 = row0[kp], u1 = row1[kp];
            o0 = fmaf(bf2f(u0 & 0xFFFFu), wcol[2 * kp], o0);
            o0 = fmaf(bf2f(u0 >> 16), wcol[2 * kp + 1], o0);
            o1 = fmaf(bf2f(u1 & 0xFFFFu), wcol[2 * kp], o1);
            o1 = fmaf(bf2f(u1 >> 16), wcol[2 * kp + 1], o1);
        }
        o0 = fmaxf(fmaf(o0, sc, sh), 0.f);
        o1 = fmaxf(fmaf(o1, sc, sh), 0.f);
        out[(size_t)n0 * 64 + lane] = o0;
        if (n0 + 1 < N) out[(size_t)(n0 + 1) * 64 + lane] = o1;
    }
}

extern "C" void kernel_launch(void* const* d_in, const int* in_sizes, int n_in,
                              void* d_out, int out_size, void* d_ws, size_t ws_size,
                              hipStream_t stream) {
    const float* x = (const float*)d_in[0];
    const int* ei = (const int*)d_in[1];
    const float* W = (const float*)d_in[2];
    // d_in[3] = bias: cancels inside BatchNorm, unused.
    const float* gamma = (const float*)d_in[4];
    const float* beta = (const float*)d_in[5];
    float* out = (float*)d_out;

    const int N = in_sizes[0] / 64;
    const int E = in_sizes[1] / 2;
    const int* src = ei;
    const int* dst = ei + E;
    const int NB = (N + 255) / 256;            // 391 (<=512 for k_scan2)
    const int B = (N + NPB - 1) >> NPB_SHIFT;  // 13 buckets

    char* ws = (char*)d_ws;
    int* deg = (int*)ws;                                     // 4N
    float* M = (float*)(ws + (size_t)4 * N);                 // 16384 B
    float* s = (float*)(ws + (size_t)4 * N + 16384);         // 256 B
    float* ss = (float*)(ws + (size_t)4 * N + 16640);        // 512 B
    int* part = (int*)(ws + (size_t)4 * N + 17152);          // 2 KB
    int* base = (int*)(ws + (size_t)4 * N + 19200);          // 2 KB
    int* bbase = (int*)(ws + (size_t)4 * N + 21248);         // 64 B
    int* bcur = (int*)(ws + (size_t)4 * N + 21312);          // 64 B
    int* offs = (int*)(ws + (size_t)4 * N + 21504);          // 4N
    int* cur = (int*)(ws + (size_t)8 * N + 21504);           // 4N
    float* dinv = (float*)(ws + (size_t)12 * N + 21504);     // 4N
    unsigned short* xb = (unsigned short*)(ws + (size_t)16 * N + 21504);   // 128N
    unsigned short* aggb = (unsigned short*)(ws + (size_t)144 * N + 21504);// 128N
    unsigned* binned = (unsigned*)(ws + (size_t)272 * N + 21504);          // 4E
    int* csr = (int*)(ws + (size_t)272 * N + (size_t)4 * E + 21504);       // 4E

    // zero deg + M + s (+ss harmless): contiguous [0, 4N+17152)
    hipMemsetAsync(deg, 0, (size_t)4 * N + 17152, stream);

    int n4 = N * 16;
    int preN = (E > n4) ? E : n4;
    k_pre<<<(preN + 255) / 256, 256, 0, stream>>>(x, dst, deg, xb, E, n4);
    k_scan1<<<NB, 256, 0, stream>>>(deg, part, N);
    k_scan2<<<1, 512, 0, stream>>>(part, base, NB);
    k_scan3<<<NB, 256, 0, stream>>>(deg, base, offs, cur, dinv, bbase, bcur, N);
    k_bin<<<(E + 4095) / 4096, 256, 0, stream>>>(src, dst, bcur, binned, E);
    k_fillL<<<256, 256, 0, stream>>>(binned, bbase, cur, csr, E, B);
    k_agg<<<2048, 256, 0, stream>>>(offs, cur, csr, xb, dinv, (unsigned*)aggb, N);
    k_moment<<<256, 256, 0, stream>>>((const unsigned*)aggb, M, s, N);
    k_bnprep2<<<1, 256, 0, stream>>>(M, s, W, gamma, beta, ss, 1.0f / (float)N);
    k_gemm2<<<NB, 256, 0, stream>>>((const unsigned*)aggb, W, ss, out, N);
}

// Round 8
// 376.431 us; speedup vs baseline: 1.1914x; 1.0559x over previous
//
#include <hip/hip_runtime.h>
#include <hip/hip_bf16.h>

#ifndef BN_EPS
#define BN_EPS 1e-5f
#endif

// ---------------------------------------------------------------------------
// N=100000, C=64, E=1600000.
// R8 = R7 with the overflow bug fixed: ALL sort placements are scan-exact
// (R7's slack-capacity coarse regions overflowed -> OOB csr writes -> crash).
//   k_pre:    deg atomics + 832-subbucket histogram + x->bf16 (no placement).
//   k_scanSub: exact scan of cnt2 -> sbase/scur + coarse cursors bcur13.
//   k_bin:    re-read edges, LDS chunk-sort into 13 coarse buckets, coalesced
//             runs at exact scan offsets (total = E, no overflow possible).
//   k_sub:    per coarse bucket: LDS chunk-sort into 64 sub-buckets.
//   k_csr:    ONE block per 128-node sub-bucket: scatter into private 8KB csr
//             window (single CU -> one L2 -> full-line writeback).
//   csr aliases binned (k_sub consumed it) -> footprint stays ~R6 (39.6MB).
// Then: agg -> moment -> bnprep2 -> gemm2. bias cancels in BN, skipped.
// ---------------------------------------------------------------------------

#define NPB 8192
#define NPB_SHIFT 13

__device__ __forceinline__ unsigned short f2bf(float f) {
    unsigned u = __float_as_uint(f);
    u += 0x7FFF + ((u >> 16) & 1);  // round-to-nearest-even
    return (unsigned short)(u >> 16);
}
__device__ __forceinline__ float bf2f(unsigned v) {
    return __uint_as_float(v << 16);
}

// deg atomics + sub-bucket (node>>7) histogram + x->bf16.
__global__ __launch_bounds__(256) void k_pre(const float* __restrict__ x,
                                             const int* __restrict__ dst,
                                             int* __restrict__ deg,
                                             unsigned short* __restrict__ xb,
                                             int* __restrict__ cnt2,
                                             int E, int n4, int SUBTOT) {
    __shared__ int h2[1024];
    int tid = threadIdx.x;
    int c0 = blockIdx.x * 4096;
    if (c0 < E) {  // block-uniform
        int cnt = min(4096, E - c0);
        for (int i = tid; i < SUBTOT; i += 256) h2[i] = 0;
        __syncthreads();
        for (int i = tid; i < cnt; i += 256) {
            int d = dst[c0 + i];
            atomicAdd(&deg[d], 1);
            atomicAdd(&h2[d >> 7], 1);
        }
        __syncthreads();
        for (int i = tid; i < SUBTOT; i += 256) {
            int v = h2[i];
            if (v > 0) atomicAdd(&cnt2[i], v);
        }
    }
    int i = blockIdx.x * 256 + tid;
    if (i < n4) {
        float4 v = ((const float4*)x)[i];
        ushort4 b;
        b.x = f2bf(v.x); b.y = f2bf(v.y); b.z = f2bf(v.z); b.w = f2bf(v.w);
        ((ushort4*)xb)[i] = b;
    }
}

// Exact scan of cnt2 -> sbase (excl, +sentinel), scur copy, coarse bcur13.
__global__ __launch_bounds__(1024) void k_scanSub(const int* __restrict__ cnt2,
                                                  int* __restrict__ sbase,
                                                  int* __restrict__ scur,
                                                  int* __restrict__ bcur13,
                                                  int SUBTOT, int E) {
    __shared__ int s[1024];
    int t = threadIdx.x;
    int v = (t < SUBTOT) ? cnt2[t] : 0;
    s[t] = v;
    __syncthreads();
    for (int off = 1; off < 1024; off <<= 1) {
        int add = (t >= off) ? s[t - off] : 0;
        __syncthreads();
        s[t] += add;
        __syncthreads();
    }
    if (t < SUBTOT) {
        int excl = s[t] - v;
        sbase[t] = excl;
        scur[t] = excl;
        if ((t & 63) == 0) bcur13[t >> 6] = excl;  // coarse bucket base
    }
    if (t == 0) sbase[SUBTOT] = E;
}

// ---- exclusive scan of deg[N] -> offs, fused dinv --------------------------
__global__ __launch_bounds__(256) void k_scan1(const int* __restrict__ deg,
                                               int* __restrict__ part, int N) {
    __shared__ int s[256];
    int tid = threadIdx.x;
    int i = blockIdx.x * 256 + tid;
    s[tid] = (i < N) ? deg[i] : 0;
    __syncthreads();
    for (int off = 128; off > 0; off >>= 1) {
        if (tid < off) s[tid] += s[tid + off];
        __syncthreads();
    }
    if (tid == 0) part[blockIdx.x] = s[0];
}

__global__ __launch_bounds__(512) void k_scan2(const int* __restrict__ part,
                                               int* __restrict__ base, int NB) {
    __shared__ int s[512];
    int t = threadIdx.x;
    int v = (t < NB) ? part[t] : 0;
    s[t] = v;
    __syncthreads();
    for (int off = 1; off < 512; off <<= 1) {
        int add = (t >= off) ? s[t - off] : 0;
        __syncthreads();
        s[t] += add;
        __syncthreads();
    }
    if (t < NB) base[t] = s[t] - v;  // exclusive
}

__global__ __launch_bounds__(256) void k_scan3(const int* __restrict__ deg,
                                               const int* __restrict__ base,
                                               int* __restrict__ offs,
                                               float* __restrict__ dinv, int N) {
    __shared__ int s[256];
    int tid = threadIdx.x;
    int i = blockIdx.x * 256 + tid;
    int v = (i < N) ? deg[i] : 0;
    s[tid] = v;
    __syncthreads();
    for (int off = 1; off < 256; off <<= 1) {
        int add = (tid >= off) ? s[tid - off] : 0;
        __syncthreads();
        s[tid] += add;
        __syncthreads();
    }
    if (i < N) {
        offs[i] = s[tid] - v + base[blockIdx.x];
        dinv[i] = rsqrtf((float)(v + 1));  // +1 = self-loop
    }
}

// Coarse bin: LDS chunk-sort 4096 edges into 13 buckets, write coalesced runs
// at exact scan offsets. packed = src (b0-16) | local13 (b17-29).
__global__ __launch_bounds__(256) void k_bin(const int* __restrict__ src,
                                             const int* __restrict__ dst,
                                             int* __restrict__ bcur13,
                                             unsigned* __restrict__ binned, int E) {
    __shared__ int hist[16], hexcl[16], hcur[16], gbase[16];
    __shared__ unsigned lout[4096];
    __shared__ unsigned char lb[4096];
    int tid = threadIdx.x;
    int c0 = blockIdx.x * 4096;
    if (c0 >= E) return;
    int cnt = min(4096, E - c0);
    if (tid < 16) hist[tid] = 0;
    __syncthreads();
    for (int i = tid; i < cnt; i += 256)
        atomicAdd(&hist[dst[c0 + i] >> NPB_SHIFT], 1);
    __syncthreads();
    if (tid == 0) {
        int acc = 0;
        for (int b = 0; b < 16; b++) { hexcl[b] = acc; hcur[b] = acc; acc += hist[b]; }
    }
    __syncthreads();
    if (tid < 16 && hist[tid] > 0) gbase[tid] = atomicAdd(&bcur13[tid], hist[tid]);
    for (int i = tid; i < cnt; i += 256) {
        int d = dst[c0 + i];
        int s = src[c0 + i];
        int b = d >> NPB_SHIFT;
        unsigned packed = (unsigned)s | ((unsigned)(d & (NPB - 1)) << 17);
        int p = atomicAdd(&hcur[b], 1);
        lout[p] = packed;
        lb[p] = (unsigned char)b;
    }
    __syncthreads();
    for (int i = tid; i < cnt; i += 256) {
        int b = lb[i];
        binned[gbase[b] + (i - hexcl[b])] = lout[i];
    }
}

// Per coarse bucket (32 blocks each): chunk-sort into 64 sub-buckets at exact
// scur offsets. out packed = src (b0-16) | local7 (b17-23).
__global__ __launch_bounds__(256) void k_sub(const unsigned* __restrict__ binned,
                                             const int* __restrict__ sbase,
                                             int* __restrict__ scur,
                                             unsigned* __restrict__ sorted2, int B) {
    __shared__ int hist[64], hexcl[64], hcur[64], gbase[64];
    __shared__ unsigned lout[4096];
    __shared__ unsigned char lb[4096];
    int b = blockIdx.x >> 5;
    int r = blockIdx.x & 31;
    if (b >= B) return;
    int tid = threadIdx.x;
    int bs = sbase[b << 6];
    int total = sbase[(b + 1) << 6] - bs;
    const unsigned* bb = binned + bs;
    for (int c0 = r * 4096; c0 < total; c0 += 32 * 4096) {
        int cnt = min(4096, total - c0);
        if (tid < 64) hist[tid] = 0;
        __syncthreads();
        for (int i = tid; i < cnt; i += 256)
            atomicAdd(&hist[(bb[c0 + i] >> 24) & 63], 1);  // local13>>7
        __syncthreads();
        if (tid == 0) {
            int acc = 0;
            for (int f = 0; f < 64; f++) { hexcl[f] = acc; hcur[f] = acc; acc += hist[f]; }
        }
        __syncthreads();
        if (tid < 64 && hist[tid] > 0)
            gbase[tid] = atomicAdd(&scur[(b << 6) + tid], hist[tid]);
        for (int i = tid; i < cnt; i += 256) {
            unsigned e = bb[c0 + i];
            int f = (e >> 24) & 63;
            unsigned rp = (e & 0x1FFFFu) | (((e >> 17) & 127u) << 17);
            int p = atomicAdd(&hcur[f], 1);
            lout[p] = rp;
            lb[p] = (unsigned char)f;
        }
        __syncthreads();
        for (int i = tid; i < cnt; i += 256) {
            int f = lb[i];
            sorted2[gbase[f] + (i - hexcl[f])] = lout[i];
        }
        __syncthreads();
    }
}

// One block per 128-node sub-bucket: LDS hist+scan, scatter into the private
// csr window (8KB avg) -> all stores from one CU, L2 merges, 1x writeback.
__global__ __launch_bounds__(256) void k_csr(const unsigned* __restrict__ sorted2,
                                             const int* __restrict__ sbase,
                                             const int* __restrict__ offs,
                                             int* __restrict__ csr, int N) {
    __shared__ int hist[128], lbase[128], lcur[128];
    int s = blockIdx.x;
    int j0 = sbase[s], j1 = sbase[s + 1];
    if (j1 <= j0) return;
    int tid = threadIdx.x;
    if (tid < 128) { hist[tid] = 0; lcur[tid] = 0; }
    __syncthreads();
    for (int j = j0 + tid; j < j1; j += 256)
        atomicAdd(&hist[sorted2[j] >> 17], 1);
    __syncthreads();
    if (tid == 0) {
        int acc = 0;
        for (int k = 0; k < 128; k++) { lbase[k] = acc; acc += hist[k]; }
    }
    __syncthreads();
    int cbase = offs[s << 7];
    for (int j = j0 + tid; j < j1; j += 256) {
        unsigned e = sorted2[j];
        int ld = e >> 17;
        int pos = cbase + lbase[ld] + atomicAdd(&lcur[ld], 1);
        csr[pos] = (int)(e & 0x1FFFFu);
    }
}

// Wave per node. lane = (half h, channel-pair p): one 4B load = 2 channels of
// one of 2 edges -> 2 edges per load instruction. Halves combined at the end.
__global__ __launch_bounds__(256) void k_agg(const int* __restrict__ offs,
                                             const int* __restrict__ deg,
                                             const int* __restrict__ csr,
                                             const unsigned short* __restrict__ xb,
                                             const float* __restrict__ dinv,
                                             unsigned* __restrict__ aggb32, int N) {
    int lane = threadIdx.x & 63;
    int p = lane & 31;   // channel pair (channels 2p, 2p+1)
    int h = lane >> 5;   // half: which edge of a pair this lane gathers
    int wid = (blockIdx.x * 256 + threadIdx.x) >> 6;
    int nw = (gridDim.x * 256) >> 6;

    for (int n = wid; n < N; n += nw) {
        float dn = dinv[n];
        unsigned sv = *(const unsigned*)(xb + (size_t)n * 64 + 2 * p);
        float wself = (h == 0) ? dn : 0.f;  // self-loop counted once
        float accx = bf2f(sv & 0xFFFFu) * wself;
        float accy = bf2f(sv >> 16) * wself;
        int j0 = offs[n];
        int j1 = j0 + deg[n];
        for (int jb = j0; jb < j1; jb += 64) {
            int cnt = min(64, j1 - jb);
            int idx = 0;
            float w = 0.f;
            if (lane < cnt) {
                idx = csr[jb + lane];
                w = dinv[idx];
            }
            int j = 0;
            for (; j + 8 <= cnt; j += 8) {
                int s0 = __shfl(idx, j + 0 + h), s1 = __shfl(idx, j + 2 + h);
                int s2 = __shfl(idx, j + 4 + h), s3 = __shfl(idx, j + 6 + h);
                float w0 = __shfl(w, j + 0 + h), w1 = __shfl(w, j + 2 + h);
                float w2 = __shfl(w, j + 4 + h), w3 = __shfl(w, j + 6 + h);
                unsigned v0 = *(const unsigned*)(xb + (size_t)s0 * 64 + 2 * p);
                unsigned v1 = *(const unsigned*)(xb + (size_t)s1 * 64 + 2 * p);
                unsigned v2 = *(const unsigned*)(xb + (size_t)s2 * 64 + 2 * p);
                unsigned v3 = *(const unsigned*)(xb + (size_t)s3 * 64 + 2 * p);
                accx = fmaf(w0, bf2f(v0 & 0xFFFFu), accx);
                accy = fmaf(w0, bf2f(v0 >> 16), accy);
                accx = fmaf(w1, bf2f(v1 & 0xFFFFu), accx);
                accy = fmaf(w1, bf2f(v1 >> 16), accy);
                accx = fmaf(w2, bf2f(v2 & 0xFFFFu), accx);
                accy = fmaf(w2, bf2f(v2 >> 16), accy);
                accx = fmaf(w3, bf2f(v3 & 0xFFFFu), accx);
                accy = fmaf(w3, bf2f(v3 >> 16), accy);
            }
            for (; j + 2 <= cnt; j += 2) {
                int s0 = __shfl(idx, j + h);
                float w0 = __shfl(w, j + h);
                unsigned v0 = *(const unsigned*)(xb + (size_t)s0 * 64 + 2 * p);
                accx = fmaf(w0, bf2f(v0 & 0xFFFFu), accx);
                accy = fmaf(w0, bf2f(v0 >> 16), accy);
            }
            if (j < cnt) {  // odd tail: half 0 contributes, half 1 gets w=0
                int s0 = __shfl(idx, j);
                float w0 = __shfl(w, j);
                if (h) w0 = 0.f;
                unsigned v0 = *(const unsigned*)(xb + (size_t)s0 * 64 + 2 * p);
                accx = fmaf(w0, bf2f(v0 & 0xFFFFu), accx);
                accy = fmaf(w0, bf2f(v0 >> 16), accy);
            }
        }
        accx += __shfl_xor(accx, 32);
        accy += __shfl_xor(accy, 32);
        if (h == 0) {
            unsigned o = (unsigned)f2bf(accx * dn) | ((unsigned)f2bf(accy * dn) << 16);
            aggb32[(size_t)n * 32 + p] = o;
        }
    }
}

// M = agg^T agg (64x64) + rowsum s. LDS-tiled 64 rows, thread owns 4x4 block.
__global__ __launch_bounds__(256) void k_moment(const unsigned* __restrict__ aggb32,
                                                float* __restrict__ M,
                                                float* __restrict__ s, int N) {
    __shared__ float tile[64 * 68];
    int t = threadIdx.x;
    int ti = t >> 4, tj = t & 15;
    float acc[4][4] = {{0.f}};
    float ssum[4] = {0.f, 0.f, 0.f, 0.f};
    int nt = (N + 63) >> 6;
    for (int tl = blockIdx.x; tl < nt; tl += gridDim.x) {
        int n0 = tl << 6;
        __syncthreads();
#pragma unroll
        for (int i = 0; i < 8; i++) {
            int idx = t + 256 * i;
            int row = idx >> 5, p = idx & 31;
            int n = n0 + row;
            unsigned v = (n < N) ? aggb32[(size_t)n * 32 + p] : 0u;
            float2 f;
            f.x = bf2f(v & 0xFFFFu);
            f.y = bf2f(v >> 16);
            *(float2*)(tile + row * 68 + 2 * p) = f;
        }
        __syncthreads();
        for (int r = 0; r < 64; r++) {
            float4 ai = *(const float4*)(tile + r * 68 + 4 * ti);
            float4 aj = *(const float4*)(tile + r * 68 + 4 * tj);
            acc[0][0] = fmaf(ai.x, aj.x, acc[0][0]);
            acc[0][1] = fmaf(ai.x, aj.y, acc[0][1]);
            acc[0][2] = fmaf(ai.x, aj.z, acc[0][2]);
            acc[0][3] = fmaf(ai.x, aj.w, acc[0][3]);
            acc[1][0] = fmaf(ai.y, aj.x, acc[1][0]);
            acc[1][1] = fmaf(ai.y, aj.y, acc[1][1]);
            acc[1][2] = fmaf(ai.y, aj.z, acc[1][2]);
            acc[1][3] = fmaf(ai.y, aj.w, acc[1][3]);
            acc[2][0] = fmaf(ai.z, aj.x, acc[2][0]);
            acc[2][1] = fmaf(ai.z, aj.y, acc[2][1]);
            acc[2][2] = fmaf(ai.z, aj.z, acc[2][2]);
            acc[2][3] = fmaf(ai.z, aj.w, acc[2][3]);
            acc[3][0] = fmaf(ai.w, aj.x, acc[3][0]);
            acc[3][1] = fmaf(ai.w, aj.y, acc[3][1]);
            acc[3][2] = fmaf(ai.w, aj.z, acc[3][2]);
            acc[3][3] = fmaf(ai.w, aj.w, acc[3][3]);
            ssum[0] += ai.x; ssum[1] += ai.y; ssum[2] += ai.z; ssum[3] += ai.w;
        }
    }
#pragma unroll
    for (int a = 0; a < 4; a++)
#pragma unroll
        for (int b = 0; b < 4; b++)
            atomicAdd(&M[(4 * ti + a) * 64 + 4 * tj + b], acc[a][b]);
    if (tj == 0) {
#pragma unroll
        for (int a = 0; a < 4; a++) atomicAdd(&s[4 * ti + a], ssum[a]);
    }
}

// scale/shift from moments: mean_c = (s@W_c)/N; E[o^2]_c = (W_c^T M W_c)/N.
__global__ __launch_bounds__(256) void k_bnprep2(const float* __restrict__ M,
                                                 const float* __restrict__ s,
                                                 const float* __restrict__ W,
                                                 const float* __restrict__ gamma,
                                                 const float* __restrict__ beta,
                                                 float* __restrict__ ss, float invN) {
    __shared__ float red[256];
    int c = threadIdx.x & 63, q = threadIdx.x >> 6;
    float wc[64];
#pragma unroll
    for (int k = 0; k < 64; k++) wc[k] = W[k * 64 + c];
    float e2p = 0.f;
    for (int i = 16 * q; i < 16 * q + 16; i++) {
        float acc = 0.f;
#pragma unroll
        for (int k = 0; k < 64; k++) acc = fmaf(M[i * 64 + k], wc[k], acc);
        e2p = fmaf(wc[i], acc, e2p);
    }
    red[threadIdx.x] = e2p;
    __syncthreads();
    if (q == 0) {
        float e2 = (red[c] + red[64 + c] + red[128 + c] + red[192 + c]) * invN;
        float mean = 0.f;
#pragma unroll
        for (int k = 0; k < 64; k++) mean = fmaf(s[k], wc[k], mean);
        mean *= invN;
        float var = e2 - mean * mean;  // biased var, matches ref
        float scale = gamma[c] * rsqrtf(var + BN_EPS);
        ss[c] = scale;
        ss[64 + c] = beta[c] - mean * scale;
    }
}

// out = BN(agg@W)+ReLU. lane=channel; agg rows staged in LDS; store = 1
// dword/lane = 256B contiguous per row (full lines, no amplification).
__global__ __launch_bounds__(256) void k_gemm2(const unsigned* __restrict__ aggb32,
                                               const float* __restrict__ W,
                                               const float* __restrict__ ss,
                                               float* __restrict__ out, int N) {
    __shared__ unsigned tile[256 * 32];
    int t = threadIdx.x;
    int lane = t & 63;
    int w = t >> 6;
    int r0 = blockIdx.x * 256;
    const uint4* gp = (const uint4*)(aggb32 + (size_t)r0 * 32);
#pragma unroll
    for (int i = 0; i < 8; i++) {
        int idx = t + 256 * i;
        int n = r0 + (idx >> 3);
        uint4 v = {0u, 0u, 0u, 0u};
        if (n < N) v = gp[idx];
        *(uint4*)(tile + idx * 4) = v;
    }
    float wcol[64];
#pragma unroll
    for (int k = 0; k < 64; k++) wcol[k] = W[k * 64 + lane];
    float sc = ss[lane], sh = ss[64 + lane];
    __syncthreads();

    for (int rr = 0; rr < 64; rr += 2) {
        int lr0 = w * 64 + rr;
        int n0 = r0 + lr0;
        if (n0 >= N) break;
        const unsigned* row0 = tile + lr0 * 32;
        const unsigned* row1 = row0 + 32;
        float o0 = 0.f, o1 = 0.f;
#pragma unroll
        for (int kp = 0; kp < 32; kp++) {
            unsigned u0 = row0[kp], u1 = row1[kp];
            o0 = fmaf(bf2f(u0 & 0xFFFFu), wcol[2 * kp], o0);
            o0 = fmaf(bf2f(u0 >> 16), wcol[2 * kp + 1], o0);
            o1 = fmaf(bf2f(u1 & 0xFFFFu), wcol[2 * kp], o1);
            o1 = fmaf(bf2f(u1 >> 16), wcol[2 * kp + 1], o1);
        }
        o0 = fmaxf(fmaf(o0, sc, sh), 0.f);
        o1 = fmaxf(fmaf(o1, sc, sh), 0.f);
        out[(size_t)n0 * 64 + lane] = o0;
        if (n0 + 1 < N) out[(size_t)(n0 + 1) * 64 + lane] = o1;
    }
}

extern "C" void kernel_launch(void* const* d_in, const int* in_sizes, int n_in,
                              void* d_out, int out_size, void* d_ws, size_t ws_size,
                              hipStream_t stream) {
    const float* x = (const float*)d_in[0];
    const int* ei = (const int*)d_in[1];
    const float* W = (const float*)d_in[2];
    // d_in[3] = bias: cancels inside BatchNorm, unused.
    const float* gamma = (const float*)d_in[4];
    const float* beta = (const float*)d_in[5];
    float* out = (float*)d_out;

    const int N = in_sizes[0] / 64;
    const int E = in_sizes[1] / 2;
    const int* src = ei;
    const int* dst = ei + E;
    const int NB = (N + 255) / 256;             // 391 (<=512 for k_scan2)
    const int B = (N + NPB - 1) >> NPB_SHIFT;   // 13 coarse buckets
    const int SUBTOT = B * 64;                  // 832 sub-buckets (<=1024)

    char* ws = (char*)d_ws;
    size_t o = 0;
    int* deg = (int*)(ws + o); o += (size_t)4 * N;   // 4N (16B-aligned: N mult of 4... 100000*4=400000, /16 ok)
    float* M = (float*)(ws + o); o += 16384;
    float* s = (float*)(ws + o); o += 256;
    float* ss = (float*)(ws + o); o += 512;
    int* cnt2 = (int*)(ws + o); o += 4096;           // 832 ints used
    size_t zero_span = o;                            // zero everything above
    int* part = (int*)(ws + o); o += 2048;
    int* base = (int*)(ws + o); o += 2048;
    int* sbase = (int*)(ws + o); o += 3584;          // SUBTOT+1 ints
    int* scur = (int*)(ws + o); o += 3584;
    int* bcur13 = (int*)(ws + o); o += 64;
    int* offs = (int*)(ws + o); o += (size_t)4 * N;
    float* dinv = (float*)(ws + o); o += (size_t)4 * N;
    unsigned short* xb = (unsigned short*)(ws + o); o += (size_t)128 * N;
    unsigned* aggb32 = (unsigned*)(ws + o); o += (size_t)128 * N;
    unsigned* binned = (unsigned*)(ws + o); o += (size_t)4 * E;
    unsigned* sorted2 = (unsigned*)(ws + o); o += (size_t)4 * E;
    int* csr = (int*)binned;  // alias: binned consumed by k_sub before k_csr

    hipMemsetAsync(deg, 0, zero_span, stream);

    int n4 = N * 16;
    int preN = (E > n4) ? E : n4;
    k_pre<<<(preN + 255) / 256, 256, 0, stream>>>(x, dst, deg, xb, cnt2, E, n4,
                                                  SUBTOT);
    k_scanSub<<<1, 1024, 0, stream>>>(cnt2, sbase, scur, bcur13, SUBTOT, E);
    k_scan1<<<NB, 256, 0, stream>>>(deg, part, N);
    k_scan2<<<1, 512, 0, stream>>>(part, base, NB);
    k_scan3<<<NB, 256, 0, stream>>>(deg, base, offs, dinv, N);
    k_bin<<<(E + 4095) / 4096, 256, 0, stream>>>(src, dst, bcur13, binned, E);
    k_sub<<<B * 32, 256, 0, stream>>>(binned, sbase, scur, sorted2, B);
    k_csr<<<SUBTOT, 256, 0, stream>>>(sorted2, sbase, offs, csr, N);
    k_agg<<<2048, 256, 0, stream>>>(offs, deg, csr, xb, dinv, aggb32, N);
    k_moment<<<256, 256, 0, stream>>>(aggb32, M, s, N);
    k_bnprep2<<<1, 256, 0, stream>>>(M, s, W, gamma, beta, ss, 1.0f / (float)N);
    k_gemm2<<<NB, 256, 0, stream>>>(aggb32, W, ss, out, N);
}

// Round 9
// 319.497 us; speedup vs baseline: 1.4037x; 1.1782x over previous
//
#include <hip/hip_runtime.h>
#include <hip/hip_bf16.h>

#ifndef BN_EPS
#define BN_EPS 1e-5f
#endif

// ---------------------------------------------------------------------------
// N=100000, C=64, E=1600000.
// R9: the hierarchical sort already counts every edge -> per-node deg atomics
// (R8's k_pre: 1.6M device atomics = ~50MB of partial-line writeback, 72us)
// are redundant. k_csr's per-sub-bucket 128-node LDS histogram IS deg, and
// offs[n] = sbase[s] + lbase[n&127] because csr is globally dst-ordered.
//   k_pre:    cnt2 (832-subbucket) histogram + x->bf16 only.
//   k_scanSub: exact scan -> sbase/scur/bcur13.
//   k_bin:    13-coarse-bucket LDS chunk-sort, coalesced runs (scan-exact).
//   k_sub:    per coarse bucket -> 64 sub-buckets (scan-exact).
//   k_csr:    one block per sub-bucket: private csr window scatter (single-CU
//             -> L2 merges) + writes deg/dinv/offs coalesced (512B each).
//   (k_scan1/2/3 and the deg memset are GONE.)
// Then: agg -> moment -> bnprep2 -> gemm2. bias cancels in BN, skipped.
// ---------------------------------------------------------------------------

#define NPB 8192
#define NPB_SHIFT 13

__device__ __forceinline__ unsigned short f2bf(float f) {
    unsigned u = __float_as_uint(f);
    u += 0x7FFF + ((u >> 16) & 1);  // round-to-nearest-even
    return (unsigned short)(u >> 16);
}
__device__ __forceinline__ float bf2f(unsigned v) {
    return __uint_as_float(v << 16);
}

// sub-bucket (node>>7) histogram + x->bf16. NO per-node atomics.
__global__ __launch_bounds__(256) void k_pre(const float* __restrict__ x,
                                             const int* __restrict__ dst,
                                             unsigned short* __restrict__ xb,
                                             int* __restrict__ cnt2,
                                             int E, int n4, int SUBTOT) {
    __shared__ int h2[1024];
    int tid = threadIdx.x;
    int c0 = blockIdx.x * 4096;
    if (c0 < E) {  // block-uniform
        int cnt = min(4096, E - c0);
        for (int i = tid; i < SUBTOT; i += 256) h2[i] = 0;
        __syncthreads();
        for (int i = tid; i < cnt; i += 256)
            atomicAdd(&h2[dst[c0 + i] >> 7], 1);
        __syncthreads();
        for (int i = tid; i < SUBTOT; i += 256) {
            int v = h2[i];
            if (v > 0) atomicAdd(&cnt2[i], v);
        }
    }
    int i = blockIdx.x * 256 + tid;
    if (i < n4) {
        float4 v = ((const float4*)x)[i];
        ushort4 b;
        b.x = f2bf(v.x); b.y = f2bf(v.y); b.z = f2bf(v.z); b.w = f2bf(v.w);
        ((ushort4*)xb)[i] = b;
    }
}

// Exact scan of cnt2 -> sbase (excl, +sentinel), scur copy, coarse bcur13.
__global__ __launch_bounds__(1024) void k_scanSub(const int* __restrict__ cnt2,
                                                  int* __restrict__ sbase,
                                                  int* __restrict__ scur,
                                                  int* __restrict__ bcur13,
                                                  int SUBTOT, int E) {
    __shared__ int s[1024];
    int t = threadIdx.x;
    int v = (t < SUBTOT) ? cnt2[t] : 0;
    s[t] = v;
    __syncthreads();
    for (int off = 1; off < 1024; off <<= 1) {
        int add = (t >= off) ? s[t - off] : 0;
        __syncthreads();
        s[t] += add;
        __syncthreads();
    }
    if (t < SUBTOT) {
        int excl = s[t] - v;
        sbase[t] = excl;
        scur[t] = excl;
        if ((t & 63) == 0) bcur13[t >> 6] = excl;  // coarse bucket base
    }
    if (t == 0) sbase[SUBTOT] = E;
}

// Coarse bin: LDS chunk-sort 4096 edges into 13 buckets, coalesced runs at
// exact scan offsets. packed = src (b0-16) | local13 (b17-29).
__global__ __launch_bounds__(256) void k_bin(const int* __restrict__ src,
                                             const int* __restrict__ dst,
                                             int* __restrict__ bcur13,
                                             unsigned* __restrict__ binned, int E) {
    __shared__ int hist[16], hexcl[16], hcur[16], gbase[16];
    __shared__ unsigned lout[4096];
    __shared__ unsigned char lb[4096];
    int tid = threadIdx.x;
    int c0 = blockIdx.x * 4096;
    if (c0 >= E) return;
    int cnt = min(4096, E - c0);
    if (tid < 16) hist[tid] = 0;
    __syncthreads();
    for (int i = tid; i < cnt; i += 256)
        atomicAdd(&hist[dst[c0 + i] >> NPB_SHIFT], 1);
    __syncthreads();
    if (tid == 0) {
        int acc = 0;
        for (int b = 0; b < 16; b++) { hexcl[b] = acc; hcur[b] = acc; acc += hist[b]; }
    }
    __syncthreads();
    if (tid < 16 && hist[tid] > 0) gbase[tid] = atomicAdd(&bcur13[tid], hist[tid]);
    for (int i = tid; i < cnt; i += 256) {
        int d = dst[c0 + i];
        int s = src[c0 + i];
        int b = d >> NPB_SHIFT;
        unsigned packed = (unsigned)s | ((unsigned)(d & (NPB - 1)) << 17);
        int p = atomicAdd(&hcur[b], 1);
        lout[p] = packed;
        lb[p] = (unsigned char)b;
    }
    __syncthreads();
    for (int i = tid; i < cnt; i += 256) {
        int b = lb[i];
        binned[gbase[b] + (i - hexcl[b])] = lout[i];
    }
}

// Per coarse bucket (32 blocks each): chunk-sort into 64 sub-buckets at exact
// scur offsets. out packed = src (b0-16) | local7 (b17-23).
__global__ __launch_bounds__(256) void k_sub(const unsigned* __restrict__ binned,
                                             const int* __restrict__ sbase,
                                             int* __restrict__ scur,
                                             unsigned* __restrict__ sorted2, int B) {
    __shared__ int hist[64], hexcl[64], hcur[64], gbase[64];
    __shared__ unsigned lout[4096];
    __shared__ unsigned char lb[4096];
    int b = blockIdx.x >> 5;
    int r = blockIdx.x & 31;
    if (b >= B) return;
    int tid = threadIdx.x;
    int bs = sbase[b << 6];
    int total = sbase[(b + 1) << 6] - bs;
    const unsigned* bb = binned + bs;
    for (int c0 = r * 4096; c0 < total; c0 += 32 * 4096) {
        int cnt = min(4096, total - c0);
        if (tid < 64) hist[tid] = 0;
        __syncthreads();
        for (int i = tid; i < cnt; i += 256)
            atomicAdd(&hist[(bb[c0 + i] >> 24) & 63], 1);  // local13>>7
        __syncthreads();
        if (tid == 0) {
            int acc = 0;
            for (int f = 0; f < 64; f++) { hexcl[f] = acc; hcur[f] = acc; acc += hist[f]; }
        }
        __syncthreads();
        if (tid < 64 && hist[tid] > 0)
            gbase[tid] = atomicAdd(&scur[(b << 6) + tid], hist[tid]);
        for (int i = tid; i < cnt; i += 256) {
            unsigned e = bb[c0 + i];
            int f = (e >> 24) & 63;
            unsigned rp = (e & 0x1FFFFu) | (((e >> 17) & 127u) << 17);
            int p = atomicAdd(&hcur[f], 1);
            lout[p] = rp;
            lb[p] = (unsigned char)f;
        }
        __syncthreads();
        for (int i = tid; i < cnt; i += 256) {
            int f = lb[i];
            sorted2[gbase[f] + (i - hexcl[f])] = lout[i];
        }
        __syncthreads();
    }
}

// One block per 128-node sub-bucket: private csr window scatter (single CU ->
// L2 merges) + deg/dinv/offs from the LDS histogram (coalesced 512B stores).
__global__ __launch_bounds__(256) void k_csr(const unsigned* __restrict__ sorted2,
                                             const int* __restrict__ sbase,
                                             int* __restrict__ deg,
                                             float* __restrict__ dinv,
                                             int* __restrict__ offs,
                                             int* __restrict__ csr, int N) {
    __shared__ int hist[128], lbase[128], lcur[128];
    int s = blockIdx.x;
    int j0 = sbase[s], j1 = sbase[s + 1];
    int tid = threadIdx.x;
    if (tid < 128) { hist[tid] = 0; lcur[tid] = 0; }
    __syncthreads();
    for (int j = j0 + tid; j < j1; j += 256)
        atomicAdd(&hist[sorted2[j] >> 17], 1);
    __syncthreads();
    if (tid == 0) {
        int acc = 0;
        for (int k = 0; k < 128; k++) { lbase[k] = acc; acc += hist[k]; }
    }
    __syncthreads();
    if (tid < 128) {  // deg / dinv / offs for this sub-bucket's 128 nodes
        int n = (s << 7) + tid;
        if (n < N) {
            int d = hist[tid];
            deg[n] = d;
            dinv[n] = rsqrtf((float)(d + 1));  // +1 = self-loop
            offs[n] = j0 + lbase[tid];         // csr is globally dst-ordered
        }
    }
    for (int j = j0 + tid; j < j1; j += 256) {
        unsigned e = sorted2[j];
        int ld = e >> 17;
        int pos = j0 + lbase[ld] + atomicAdd(&lcur[ld], 1);
        csr[pos] = (int)(e & 0x1FFFFu);
    }
}

// Wave per node. lane = (half h, channel-pair p): one 4B load = 2 channels of
// one of 2 edges -> 2 edges per load instruction. Halves combined at the end.
__global__ __launch_bounds__(256) void k_agg(const int* __restrict__ offs,
                                             const int* __restrict__ deg,
                                             const int* __restrict__ csr,
                                             const unsigned short* __restrict__ xb,
                                             const float* __restrict__ dinv,
                                             unsigned* __restrict__ aggb32, int N) {
    int lane = threadIdx.x & 63;
    int p = lane & 31;   // channel pair (channels 2p, 2p+1)
    int h = lane >> 5;   // half: which edge of a pair this lane gathers
    int wid = (blockIdx.x * 256 + threadIdx.x) >> 6;
    int nw = (gridDim.x * 256) >> 6;

    for (int n = wid; n < N; n += nw) {
        float dn = dinv[n];
        unsigned sv = *(const unsigned*)(xb + (size_t)n * 64 + 2 * p);
        float wself = (h == 0) ? dn : 0.f;  // self-loop counted once
        float accx = bf2f(sv & 0xFFFFu) * wself;
        float accy = bf2f(sv >> 16) * wself;
        int j0 = offs[n];
        int j1 = j0 + deg[n];
        for (int jb = j0; jb < j1; jb += 64) {
            int cnt = min(64, j1 - jb);
            int idx = 0;
            float w = 0.f;
            if (lane < cnt) {
                idx = csr[jb + lane];
                w = dinv[idx];
            }
            int j = 0;
            for (; j + 8 <= cnt; j += 8) {
                int s0 = __shfl(idx, j + 0 + h), s1 = __shfl(idx, j + 2 + h);
                int s2 = __shfl(idx, j + 4 + h), s3 = __shfl(idx, j + 6 + h);
                float w0 = __shfl(w, j + 0 + h), w1 = __shfl(w, j + 2 + h);
                float w2 = __shfl(w, j + 4 + h), w3 = __shfl(w, j + 6 + h);
                unsigned v0 = *(const unsigned*)(xb + (size_t)s0 * 64 + 2 * p);
                unsigned v1 = *(const unsigned*)(xb + (size_t)s1 * 64 + 2 * p);
                unsigned v2 = *(const unsigned*)(xb + (size_t)s2 * 64 + 2 * p);
                unsigned v3 = *(const unsigned*)(xb + (size_t)s3 * 64 + 2 * p);
                accx = fmaf(w0, bf2f(v0 & 0xFFFFu), accx);
                accy = fmaf(w0, bf2f(v0 >> 16), accy);
                accx = fmaf(w1, bf2f(v1 & 0xFFFFu), accx);
                accy = fmaf(w1, bf2f(v1 >> 16), accy);
                accx = fmaf(w2, bf2f(v2 & 0xFFFFu), accx);
                accy = fmaf(w2, bf2f(v2 >> 16), accy);
                accx = fmaf(w3, bf2f(v3 & 0xFFFFu), accx);
                accy = fmaf(w3, bf2f(v3 >> 16), accy);
            }
            for (; j + 2 <= cnt; j += 2) {
                int s0 = __shfl(idx, j + h);
                float w0 = __shfl(w, j + h);
                unsigned v0 = *(const unsigned*)(xb + (size_t)s0 * 64 + 2 * p);
                accx = fmaf(w0, bf2f(v0 & 0xFFFFu), accx);
                accy = fmaf(w0, bf2f(v0 >> 16), accy);
            }
            if (j < cnt) {  // odd tail: half 0 contributes, half 1 gets w=0
                int s0 = __shfl(idx, j);
                float w0 = __shfl(w, j);
                if (h) w0 = 0.f;
                unsigned v0 = *(const unsigned*)(xb + (size_t)s0 * 64 + 2 * p);
                accx = fmaf(w0, bf2f(v0 & 0xFFFFu), accx);
                accy = fmaf(w0, bf2f(v0 >> 16), accy);
            }
        }
        accx += __shfl_xor(accx, 32);
        accy += __shfl_xor(accy, 32);
        if (h == 0) {
            unsigned o = (unsigned)f2bf(accx * dn) | ((unsigned)f2bf(accy * dn) << 16);
            aggb32[(size_t)n * 32 + p] = o;
        }
    }
}

// M = agg^T agg (64x64) + rowsum s. LDS-tiled 64 rows, thread owns 4x4 block.
__global__ __launch_bounds__(256) void k_moment(const unsigned* __restrict__ aggb32,
                                                float* __restrict__ M,
                                                float* __restrict__ s, int N) {
    __shared__ float tile[64 * 68];
    int t = threadIdx.x;
    int ti = t >> 4, tj = t & 15;
    float acc[4][4] = {{0.f}};
    float ssum[4] = {0.f, 0.f, 0.f, 0.f};
    int nt = (N + 63) >> 6;
    for (int tl = blockIdx.x; tl < nt; tl += gridDim.x) {
        int n0 = tl << 6;
        __syncthreads();
#pragma unroll
        for (int i = 0; i < 8; i++) {
            int idx = t + 256 * i;
            int row = idx >> 5, p = idx & 31;
            int n = n0 + row;
            unsigned v = (n < N) ? aggb32[(size_t)n * 32 + p] : 0u;
            float2 f;
            f.x = bf2f(v & 0xFFFFu);
            f.y = bf2f(v >> 16);
            *(float2*)(tile + row * 68 + 2 * p) = f;
        }
        __syncthreads();
        for (int r = 0; r < 64; r++) {
            float4 ai = *(const float4*)(tile + r * 68 + 4 * ti);
            float4 aj = *(const float4*)(tile + r * 68 + 4 * tj);
            acc[0][0] = fmaf(ai.x, aj.x, acc[0][0]);
            acc[0][1] = fmaf(ai.x, aj.y, acc[0][1]);
            acc[0][2] = fmaf(ai.x, aj.z, acc[0][2]);
            acc[0][3] = fmaf(ai.x, aj.w, acc[0][3]);
            acc[1][0] = fmaf(ai.y, aj.x, acc[1][0]);
            acc[1][1] = fmaf(ai.y, aj.y, acc[1][1]);
            acc[1][2] = fmaf(ai.y, aj.z, acc[1][2]);
            acc[1][3] = fmaf(ai.y, aj.w, acc[1][3]);
            acc[2][0] = fmaf(ai.z, aj.x, acc[2][0]);
            acc[2][1] = fmaf(ai.z, aj.y, acc[2][1]);
            acc[2][2] = fmaf(ai.z, aj.z, acc[2][2]);
            acc[2][3] = fmaf(ai.z, aj.w, acc[2][3]);
            acc[3][0] = fmaf(ai.w, aj.x, acc[3][0]);
            acc[3][1] = fmaf(ai.w, aj.y, acc[3][1]);
            acc[3][2] = fmaf(ai.w, aj.z, acc[3][2]);
            acc[3][3] = fmaf(ai.w, aj.w, acc[3][3]);
            ssum[0] += ai.x; ssum[1] += ai.y; ssum[2] += ai.z; ssum[3] += ai.w;
        }
    }
#pragma unroll
    for (int a = 0; a < 4; a++)
#pragma unroll
        for (int b = 0; b < 4; b++)
            atomicAdd(&M[(4 * ti + a) * 64 + 4 * tj + b], acc[a][b]);
    if (tj == 0) {
#pragma unroll
        for (int a = 0; a < 4; a++) atomicAdd(&s[4 * ti + a], ssum[a]);
    }
}

// scale/shift from moments: mean_c = (s@W_c)/N; E[o^2]_c = (W_c^T M W_c)/N.
__global__ __launch_bounds__(256) void k_bnprep2(const float* __restrict__ M,
                                                 const float* __restrict__ s,
                                                 const float* __restrict__ W,
                                                 const float* __restrict__ gamma,
                                                 const float* __restrict__ beta,
                                                 float* __restrict__ ss, float invN) {
    __shared__ float red[256];
    int c = threadIdx.x & 63, q = threadIdx.x >> 6;
    float wc[64];
#pragma unroll
    for (int k = 0; k < 64; k++) wc[k] = W[k * 64 + c];
    float e2p = 0.f;
    for (int i = 16 * q; i < 16 * q + 16; i++) {
        float acc = 0.f;
#pragma unroll
        for (int k = 0; k < 64; k++) acc = fmaf(M[i * 64 + k], wc[k], acc);
        e2p = fmaf(wc[i], acc, e2p);
    }
    red[threadIdx.x] = e2p;
    __syncthreads();
    if (q == 0) {
        float e2 = (red[c] + red[64 + c] + red[128 + c] + red[192 + c]) * invN;
        float mean = 0.f;
#pragma unroll
        for (int k = 0; k < 64; k++) mean = fmaf(s[k], wc[k], mean);
        mean *= invN;
        float var = e2 - mean * mean;  // biased var, matches ref
        float scale = gamma[c] * rsqrtf(var + BN_EPS);
        ss[c] = scale;
        ss[64 + c] = beta[c] - mean * scale;
    }
}

// out = BN(agg@W)+ReLU. lane=channel; agg rows staged in LDS; store = 1
// dword/lane = 256B contiguous per row (full lines, no amplification).
__global__ __launch_bounds__(256) void k_gemm2(const unsigned* __restrict__ aggb32,
                                               const float* __restrict__ W,
                                               const float* __restrict__ ss,
                                               float* __restrict__ out, int N) {
    __shared__ unsigned tile[256 * 32];
    int t = threadIdx.x;
    int lane = t & 63;
    int w = t >> 6;
    int r0 = blockIdx.x * 256;
    const uint4* gp = (const uint4*)(aggb32 + (size_t)r0 * 32);
#pragma unroll
    for (int i = 0; i < 8; i++) {
        int idx = t + 256 * i;
        int n = r0 + (idx >> 3);
        uint4 v = {0u, 0u, 0u, 0u};
        if (n < N) v = gp[idx];
        *(uint4*)(tile + idx * 4) = v;
    }
    float wcol[64];
#pragma unroll
    for (int k = 0; k < 64; k++) wcol[k] = W[k * 64 + lane];
    float sc = ss[lane], sh = ss[64 + lane];
    __syncthreads();

    for (int rr = 0; rr < 64; rr += 2) {
        int lr0 = w * 64 + rr;
        int n0 = r0 + lr0;
        if (n0 >= N) break;
        const unsigned* row0 = tile + lr0 * 32;
        const unsigned* row1 = row0 + 32;
        float o0 = 0.f, o1 = 0.f;
#pragma unroll
        for (int kp = 0; kp < 32; kp++) {
            unsigned u0 = row0[kp], u1 = row1[kp];
            o0 = fmaf(bf2f(u0 & 0xFFFFu), wcol[2 * kp], o0);
            o0 = fmaf(bf2f(u0 >> 16), wcol[2 * kp + 1], o0);
            o1 = fmaf(bf2f(u1 & 0xFFFFu), wcol[2 * kp], o1);
            o1 = fmaf(bf2f(u1 >> 16), wcol[2 * kp + 1], o1);
        }
        o0 = fmaxf(fmaf(o0, sc, sh), 0.f);
        o1 = fmaxf(fmaf(o1, sc, sh), 0.f);
        out[(size_t)n0 * 64 + lane] = o0;
        if (n0 + 1 < N) out[(size_t)(n0 + 1) * 64 + lane] = o1;
    }
}

extern "C" void kernel_launch(void* const* d_in, const int* in_sizes, int n_in,
                              void* d_out, int out_size, void* d_ws, size_t ws_size,
                              hipStream_t stream) {
    const float* x = (const float*)d_in[0];
    const int* ei = (const int*)d_in[1];
    const float* W = (const float*)d_in[2];
    // d_in[3] = bias: cancels inside BatchNorm, unused.
    const float* gamma = (const float*)d_in[4];
    const float* beta = (const float*)d_in[5];
    float* out = (float*)d_out;

    const int N = in_sizes[0] / 64;
    const int E = in_sizes[1] / 2;
    const int* src = ei;
    const int* dst = ei + E;
    const int NB = (N + 255) / 256;             // 391
    const int B = (N + NPB - 1) >> NPB_SHIFT;   // 13 coarse buckets
    const int SUBTOT = B * 64;                  // 832 sub-buckets (<=1024)

    char* ws = (char*)d_ws;
    size_t o = 0;
    float* M = (float*)(ws + o); o += 16384;
    float* s = (float*)(ws + o); o += 256;
    float* ss = (float*)(ws + o); o += 512;
    int* cnt2 = (int*)(ws + o); o += 4096;           // 832 ints used
    size_t zero_span = o;                            // zero M,s,ss,cnt2 only
    int* sbase = (int*)(ws + o); o += 3584;          // SUBTOT+1 ints
    int* scur = (int*)(ws + o); o += 3584;
    int* bcur13 = (int*)(ws + o); o += 64;
    int* deg = (int*)(ws + o); o += (size_t)4 * N;
    int* offs = (int*)(ws + o); o += (size_t)4 * N;
    float* dinv = (float*)(ws + o); o += (size_t)4 * N;
    unsigned short* xb = (unsigned short*)(ws + o); o += (size_t)128 * N;
    unsigned* aggb32 = (unsigned*)(ws + o); o += (size_t)128 * N;
    unsigned* binned = (unsigned*)(ws + o); o += (size_t)4 * E;
    unsigned* sorted2 = (unsigned*)(ws + o); o += (size_t)4 * E;
    int* csr = (int*)binned;  // alias: binned consumed by k_sub before k_csr

    hipMemsetAsync(M, 0, zero_span, stream);

    int n4 = N * 16;
    int preN = (E > n4 * 16 / 16) ? E : n4;  // max(E edges via 4096-chunks, n4 via 256)
    int preBlocks = ((preN + 255) / 256 > (E + 4095) / 4096) ? (preN + 255) / 256
                                                             : (E + 4095) / 4096;
    k_pre<<<preBlocks, 256, 0, stream>>>(x, dst, xb, cnt2, E, n4, SUBTOT);
    k_scanSub<<<1, 1024, 0, stream>>>(cnt2, sbase, scur, bcur13, SUBTOT, E);
    k_bin<<<(E + 4095) / 4096, 256, 0, stream>>>(src, dst, bcur13, binned, E);
    k_sub<<<B * 32, 256, 0, stream>>>(binned, sbase, scur, sorted2, B);
    k_csr<<<SUBTOT, 256, 0, stream>>>(sorted2, sbase, deg, dinv, offs, csr, N);
    k_agg<<<2048, 256, 0, stream>>>(offs, deg, csr, xb, dinv, aggb32, N);
    k_moment<<<256, 256, 0, stream>>>(aggb32, M, s, N);
    k_bnprep2<<<1, 256, 0, stream>>>(M, s, W, gamma, beta, ss, 1.0f / (float)N);
    k_gemm2<<<NB, 256, 0, stream>>>(aggb32, W, ss, out, N);
}

// Round 10
// 261.831 us; speedup vs baseline: 1.7128x; 1.2202x over previous
//
#include <hip/hip_runtime.h>
#include <hip/hip_bf16.h>

#ifndef BN_EPS
#define BN_EPS 1e-5f
#endif

// ---------------------------------------------------------------------------
// N=100000, C=64, E=1600000.
// R10: replace k_moment (72us: 1M tail atomics = 16.6MB writeback + 1-wave/SIMD
// LDS-latency-bound inner loop) with k_gemm1 = store-less k_gemm2 clone:
// lane=channel, W columns in VGPRs, agg rows LDS-staged/broadcast; per-lane
// psum/psq registers; block LDS-reduce -> 128 atomics/block (50K total, 0.8MB).
// Pipeline: pre(hist+bf16) -> scanSub -> bin -> sub -> csr(+deg/dinv/offs)
//           -> agg -> gemm1(stats) -> bnprep -> gemm2(BN+ReLU, full-line).
// bias cancels inside BatchNorm, skipped.
// ---------------------------------------------------------------------------

#define NPB 8192
#define NPB_SHIFT 13

__device__ __forceinline__ unsigned short f2bf(float f) {
    unsigned u = __float_as_uint(f);
    u += 0x7FFF + ((u >> 16) & 1);  // round-to-nearest-even
    return (unsigned short)(u >> 16);
}
__device__ __forceinline__ float bf2f(unsigned v) {
    return __uint_as_float(v << 16);
}

// sub-bucket (node>>7) histogram + x->bf16. NO per-node atomics.
__global__ __launch_bounds__(256) void k_pre(const float* __restrict__ x,
                                             const int* __restrict__ dst,
                                             unsigned short* __restrict__ xb,
                                             int* __restrict__ cnt2,
                                             int E, int n4, int SUBTOT) {
    __shared__ int h2[1024];
    int tid = threadIdx.x;
    int c0 = blockIdx.x * 4096;
    if (c0 < E) {  // block-uniform
        int cnt = min(4096, E - c0);
        for (int i = tid; i < SUBTOT; i += 256) h2[i] = 0;
        __syncthreads();
        for (int i = tid; i < cnt; i += 256)
            atomicAdd(&h2[dst[c0 + i] >> 7], 1);
        __syncthreads();
        for (int i = tid; i < SUBTOT; i += 256) {
            int v = h2[i];
            if (v > 0) atomicAdd(&cnt2[i], v);
        }
    }
    int i = blockIdx.x * 256 + tid;
    if (i < n4) {
        float4 v = ((const float4*)x)[i];
        ushort4 b;
        b.x = f2bf(v.x); b.y = f2bf(v.y); b.z = f2bf(v.z); b.w = f2bf(v.w);
        ((ushort4*)xb)[i] = b;
    }
}

// Exact scan of cnt2 -> sbase (excl, +sentinel), scur copy, coarse bcur13.
__global__ __launch_bounds__(1024) void k_scanSub(const int* __restrict__ cnt2,
                                                  int* __restrict__ sbase,
                                                  int* __restrict__ scur,
                                                  int* __restrict__ bcur13,
                                                  int SUBTOT, int E) {
    __shared__ int s[1024];
    int t = threadIdx.x;
    int v = (t < SUBTOT) ? cnt2[t] : 0;
    s[t] = v;
    __syncthreads();
    for (int off = 1; off < 1024; off <<= 1) {
        int add = (t >= off) ? s[t - off] : 0;
        __syncthreads();
        s[t] += add;
        __syncthreads();
    }
    if (t < SUBTOT) {
        int excl = s[t] - v;
        sbase[t] = excl;
        scur[t] = excl;
        if ((t & 63) == 0) bcur13[t >> 6] = excl;  // coarse bucket base
    }
    if (t == 0) sbase[SUBTOT] = E;
}

// Coarse bin: LDS chunk-sort 4096 edges into 13 buckets, coalesced runs at
// exact scan offsets. packed = src (b0-16) | local13 (b17-29).
__global__ __launch_bounds__(256) void k_bin(const int* __restrict__ src,
                                             const int* __restrict__ dst,
                                             int* __restrict__ bcur13,
                                             unsigned* __restrict__ binned, int E) {
    __shared__ int hist[16], hexcl[16], hcur[16], gbase[16];
    __shared__ unsigned lout[4096];
    __shared__ unsigned char lb[4096];
    int tid = threadIdx.x;
    int c0 = blockIdx.x * 4096;
    if (c0 >= E) return;
    int cnt = min(4096, E - c0);
    if (tid < 16) hist[tid] = 0;
    __syncthreads();
    for (int i = tid; i < cnt; i += 256)
        atomicAdd(&hist[dst[c0 + i] >> NPB_SHIFT], 1);
    __syncthreads();
    if (tid == 0) {
        int acc = 0;
        for (int b = 0; b < 16; b++) { hexcl[b] = acc; hcur[b] = acc; acc += hist[b]; }
    }
    __syncthreads();
    if (tid < 16 && hist[tid] > 0) gbase[tid] = atomicAdd(&bcur13[tid], hist[tid]);
    for (int i = tid; i < cnt; i += 256) {
        int d = dst[c0 + i];
        int s = src[c0 + i];
        int b = d >> NPB_SHIFT;
        unsigned packed = (unsigned)s | ((unsigned)(d & (NPB - 1)) << 17);
        int p = atomicAdd(&hcur[b], 1);
        lout[p] = packed;
        lb[p] = (unsigned char)b;
    }
    __syncthreads();
    for (int i = tid; i < cnt; i += 256) {
        int b = lb[i];
        binned[gbase[b] + (i - hexcl[b])] = lout[i];
    }
}

// Per coarse bucket (32 blocks each): chunk-sort into 64 sub-buckets at exact
// scur offsets. out packed = src (b0-16) | local7 (b17-23).
__global__ __launch_bounds__(256) void k_sub(const unsigned* __restrict__ binned,
                                             const int* __restrict__ sbase,
                                             int* __restrict__ scur,
                                             unsigned* __restrict__ sorted2, int B) {
    __shared__ int hist[64], hexcl[64], hcur[64], gbase[64];
    __shared__ unsigned lout[4096];
    __shared__ unsigned char lb[4096];
    int b = blockIdx.x >> 5;
    int r = blockIdx.x & 31;
    if (b >= B) return;
    int tid = threadIdx.x;
    int bs = sbase[b << 6];
    int total = sbase[(b + 1) << 6] - bs;
    const unsigned* bb = binned + bs;
    for (int c0 = r * 4096; c0 < total; c0 += 32 * 4096) {
        int cnt = min(4096, total - c0);
        if (tid < 64) hist[tid] = 0;
        __syncthreads();
        for (int i = tid; i < cnt; i += 256)
            atomicAdd(&hist[(bb[c0 + i] >> 24) & 63], 1);  // local13>>7
        __syncthreads();
        if (tid == 0) {
            int acc = 0;
            for (int f = 0; f < 64; f++) { hexcl[f] = acc; hcur[f] = acc; acc += hist[f]; }
        }
        __syncthreads();
        if (tid < 64 && hist[tid] > 0)
            gbase[tid] = atomicAdd(&scur[(b << 6) + tid], hist[tid]);
        for (int i = tid; i < cnt; i += 256) {
            unsigned e = bb[c0 + i];
            int f = (e >> 24) & 63;
            unsigned rp = (e & 0x1FFFFu) | (((e >> 17) & 127u) << 17);
            int p = atomicAdd(&hcur[f], 1);
            lout[p] = rp;
            lb[p] = (unsigned char)f;
        }
        __syncthreads();
        for (int i = tid; i < cnt; i += 256) {
            int f = lb[i];
            sorted2[gbase[f] + (i - hexcl[f])] = lout[i];
        }
        __syncthreads();
    }
}

// One block per 128-node sub-bucket: private csr window scatter (single CU ->
// L2 merges) + deg/dinv/offs from the LDS histogram (coalesced 512B stores).
__global__ __launch_bounds__(256) void k_csr(const unsigned* __restrict__ sorted2,
                                             const int* __restrict__ sbase,
                                             int* __restrict__ deg,
                                             float* __restrict__ dinv,
                                             int* __restrict__ offs,
                                             int* __restrict__ csr, int N) {
    __shared__ int hist[128], lbase[128], lcur[128];
    int s = blockIdx.x;
    int j0 = sbase[s], j1 = sbase[s + 1];
    int tid = threadIdx.x;
    if (tid < 128) { hist[tid] = 0; lcur[tid] = 0; }
    __syncthreads();
    for (int j = j0 + tid; j < j1; j += 256)
        atomicAdd(&hist[sorted2[j] >> 17], 1);
    __syncthreads();
    if (tid == 0) {
        int acc = 0;
        for (int k = 0; k < 128; k++) { lbase[k] = acc; acc += hist[k]; }
    }
    __syncthreads();
    if (tid < 128) {  // deg / dinv / offs for this sub-bucket's 128 nodes
        int n = (s << 7) + tid;
        if (n < N) {
            int d = hist[tid];
            deg[n] = d;
            dinv[n] = rsqrtf((float)(d + 1));  // +1 = self-loop
            offs[n] = j0 + lbase[tid];         // csr is globally dst-ordered
        }
    }
    for (int j = j0 + tid; j < j1; j += 256) {
        unsigned e = sorted2[j];
        int ld = e >> 17;
        int pos = j0 + lbase[ld] + atomicAdd(&lcur[ld], 1);
        csr[pos] = (int)(e & 0x1FFFFu);
    }
}

// Wave per node. lane = (half h, channel-pair p): one 4B load = 2 channels of
// one of 2 edges -> 2 edges per load instruction. Halves combined at the end.
__global__ __launch_bounds__(256) void k_agg(const int* __restrict__ offs,
                                             const int* __restrict__ deg,
                                             const int* __restrict__ csr,
                                             const unsigned short* __restrict__ xb,
                                             const float* __restrict__ dinv,
                                             unsigned* __restrict__ aggb32, int N) {
    int lane = threadIdx.x & 63;
    int p = lane & 31;   // channel pair (channels 2p, 2p+1)
    int h = lane >> 5;   // half: which edge of a pair this lane gathers
    int wid = (blockIdx.x * 256 + threadIdx.x) >> 6;
    int nw = (gridDim.x * 256) >> 6;

    for (int n = wid; n < N; n += nw) {
        float dn = dinv[n];
        unsigned sv = *(const unsigned*)(xb + (size_t)n * 64 + 2 * p);
        float wself = (h == 0) ? dn : 0.f;  // self-loop counted once
        float accx = bf2f(sv & 0xFFFFu) * wself;
        float accy = bf2f(sv >> 16) * wself;
        int j0 = offs[n];
        int j1 = j0 + deg[n];
        for (int jb = j0; jb < j1; jb += 64) {
            int cnt = min(64, j1 - jb);
            int idx = 0;
            float w = 0.f;
            if (lane < cnt) {
                idx = csr[jb + lane];
                w = dinv[idx];
            }
            int j = 0;
            for (; j + 8 <= cnt; j += 8) {
                int s0 = __shfl(idx, j + 0 + h), s1 = __shfl(idx, j + 2 + h);
                int s2 = __shfl(idx, j + 4 + h), s3 = __shfl(idx, j + 6 + h);
                float w0 = __shfl(w, j + 0 + h), w1 = __shfl(w, j + 2 + h);
                float w2 = __shfl(w, j + 4 + h), w3 = __shfl(w, j + 6 + h);
                unsigned v0 = *(const unsigned*)(xb + (size_t)s0 * 64 + 2 * p);
                unsigned v1 = *(const unsigned*)(xb + (size_t)s1 * 64 + 2 * p);
                unsigned v2 = *(const unsigned*)(xb + (size_t)s2 * 64 + 2 * p);
                unsigned v3 = *(const unsigned*)(xb + (size_t)s3 * 64 + 2 * p);
                accx = fmaf(w0, bf2f(v0 & 0xFFFFu), accx);
                accy = fmaf(w0, bf2f(v0 >> 16), accy);
                accx = fmaf(w1, bf2f(v1 & 0xFFFFu), accx);
                accy = fmaf(w1, bf2f(v1 >> 16), accy);
                accx = fmaf(w2, bf2f(v2 & 0xFFFFu), accx);
                accy = fmaf(w2, bf2f(v2 >> 16), accy);
                accx = fmaf(w3, bf2f(v3 & 0xFFFFu), accx);
                accy = fmaf(w3, bf2f(v3 >> 16), accy);
            }
            for (; j + 2 <= cnt; j += 2) {
                int s0 = __shfl(idx, j + h);
                float w0 = __shfl(w, j + h);
                unsigned v0 = *(const unsigned*)(xb + (size_t)s0 * 64 + 2 * p);
                accx = fmaf(w0, bf2f(v0 & 0xFFFFu), accx);
                accy = fmaf(w0, bf2f(v0 >> 16), accy);
            }
            if (j < cnt) {  // odd tail: half 0 contributes, half 1 gets w=0
                int s0 = __shfl(idx, j);
                float w0 = __shfl(w, j);
                if (h) w0 = 0.f;
                unsigned v0 = *(const unsigned*)(xb + (size_t)s0 * 64 + 2 * p);
                accx = fmaf(w0, bf2f(v0 & 0xFFFFu), accx);
                accy = fmaf(w0, bf2f(v0 >> 16), accy);
            }
        }
        accx += __shfl_xor(accx, 32);
        accy += __shfl_xor(accy, 32);
        if (h == 0) {
            unsigned o = (unsigned)f2bf(accx * dn) | ((unsigned)f2bf(accy * dn) << 16);
            aggb32[(size_t)n * 32 + p] = o;
        }
    }
}

// Stats pass: o = agg@W per row (same structure as k_gemm2, NO stores).
// lane=channel -> psum/psq in registers; LDS-reduce across 4 waves; 128
// atomics per block total (50K device-wide, ~0.8MB writeback).
__global__ __launch_bounds__(256) void k_gemm1(const unsigned* __restrict__ aggb32,
                                               const float* __restrict__ W,
                                               float* __restrict__ stats, int N) {
    __shared__ unsigned tile[256 * 32];
    __shared__ float red[512];  // [2][4][64]
    int t = threadIdx.x;
    int lane = t & 63;
    int w = t >> 6;
    int r0 = blockIdx.x * 256;
    const uint4* gp = (const uint4*)(aggb32 + (size_t)r0 * 32);
#pragma unroll
    for (int i = 0; i < 8; i++) {
        int idx = t + 256 * i;
        int n = r0 + (idx >> 3);
        uint4 v = {0u, 0u, 0u, 0u};
        if (n < N) v = gp[idx];
        *(uint4*)(tile + idx * 4) = v;
    }
    float wcol[64];
#pragma unroll
    for (int k = 0; k < 64; k++) wcol[k] = W[k * 64 + lane];
    __syncthreads();

    float psum = 0.f, psq = 0.f;
    for (int rr = 0; rr < 64; rr += 2) {
        int lr0 = w * 64 + rr;
        int n0 = r0 + lr0;
        if (n0 >= N) break;
        const unsigned* row0 = tile + lr0 * 32;
        const unsigned* row1 = row0 + 32;
        float o0 = 0.f, o1 = 0.f;
#pragma unroll
        for (int kp = 0; kp < 32; kp++) {
            unsigned u0 = row0[kp], u1 = row1[kp];
            o0 = fmaf(bf2f(u0 & 0xFFFFu), wcol[2 * kp], o0);
            o0 = fmaf(bf2f(u0 >> 16), wcol[2 * kp + 1], o0);
            o1 = fmaf(bf2f(u1 & 0xFFFFu), wcol[2 * kp], o1);
            o1 = fmaf(bf2f(u1 >> 16), wcol[2 * kp + 1], o1);
        }
        psum += o0;
        psq = fmaf(o0, o0, psq);
        if (n0 + 1 < N) {
            psum += o1;
            psq = fmaf(o1, o1, psq);
        }
    }
    red[w * 64 + lane] = psum;
    red[256 + w * 64 + lane] = psq;
    __syncthreads();
    if (w == 0) {
        float s = red[lane] + red[64 + lane] + red[128 + lane] + red[192 + lane];
        atomicAdd(&stats[lane], s);
    } else if (w == 1) {
        float q = red[256 + lane] + red[320 + lane] + red[384 + lane] + red[448 + lane];
        atomicAdd(&stats[64 + lane], q);
    }
}

__global__ void k_bnprep(const float* __restrict__ stats,
                         const float* __restrict__ gamma,
                         const float* __restrict__ beta,
                         float* __restrict__ ss, float invN) {
    int c = threadIdx.x;  // 64 threads
    float mean = stats[c] * invN;
    float var = stats[64 + c] * invN - mean * mean;  // biased var, matches ref
    float scale = gamma[c] * rsqrtf(var + BN_EPS);
    ss[c] = scale;
    ss[64 + c] = beta[c] - mean * scale;
}

// out = BN(agg@W)+ReLU. lane=channel; agg rows staged in LDS; store = 1
// dword/lane = 256B contiguous per row (full lines, no amplification).
__global__ __launch_bounds__(256) void k_gemm2(const unsigned* __restrict__ aggb32,
                                               const float* __restrict__ W,
                                               const float* __restrict__ ss,
                                               float* __restrict__ out, int N) {
    __shared__ unsigned tile[256 * 32];
    int t = threadIdx.x;
    int lane = t & 63;
    int w = t >> 6;
    int r0 = blockIdx.x * 256;
    const uint4* gp = (const uint4*)(aggb32 + (size_t)r0 * 32);
#pragma unroll
    for (int i = 0; i < 8; i++) {
        int idx = t + 256 * i;
        int n = r0 + (idx >> 3);
        uint4 v = {0u, 0u, 0u, 0u};
        if (n < N) v = gp[idx];
        *(uint4*)(tile + idx * 4) = v;
    }
    float wcol[64];
#pragma unroll
    for (int k = 0; k < 64; k++) wcol[k] = W[k * 64 + lane];
    float sc = ss[lane], sh = ss[64 + lane];
    __syncthreads();

    for (int rr = 0; rr < 64; rr += 2) {
        int lr0 = w * 64 + rr;
        int n0 = r0 + lr0;
        if (n0 >= N) break;
        const unsigned* row0 = tile + lr0 * 32;
        const unsigned* row1 = row0 + 32;
        float o0 = 0.f, o1 = 0.f;
#pragma unroll
        for (int kp = 0; kp < 32; kp++) {
            unsigned u0 = row0[kp], u1 = row1[kp];
            o0 = fmaf(bf2f(u0 & 0xFFFFu), wcol[2 * kp], o0);
            o0 = fmaf(bf2f(u0 >> 16), wcol[2 * kp + 1], o0);
            o1 = fmaf(bf2f(u1 & 0xFFFFu), wcol[2 * kp], o1);
            o1 = fmaf(bf2f(u1 >> 16), wcol[2 * kp + 1], o1);
        }
        o0 = fmaxf(fmaf(o0, sc, sh), 0.f);
        o1 = fmaxf(fmaf(o1, sc, sh), 0.f);
        out[(size_t)n0 * 64 + lane] = o0;
        if (n0 + 1 < N) out[(size_t)(n0 + 1) * 64 + lane] = o1;
    }
}

extern "C" void kernel_launch(void* const* d_in, const int* in_sizes, int n_in,
                              void* d_out, int out_size, void* d_ws, size_t ws_size,
                              hipStream_t stream) {
    const float* x = (const float*)d_in[0];
    const int* ei = (const int*)d_in[1];
    const float* W = (const float*)d_in[2];
    // d_in[3] = bias: cancels inside BatchNorm, unused.
    const float* gamma = (const float*)d_in[4];
    const float* beta = (const float*)d_in[5];
    float* out = (float*)d_out;

    const int N = in_sizes[0] / 64;
    const int E = in_sizes[1] / 2;
    const int* src = ei;
    const int* dst = ei + E;
    const int NB = (N + 255) / 256;             // 391
    const int B = (N + NPB - 1) >> NPB_SHIFT;   // 13 coarse buckets
    const int SUBTOT = B * 64;                  // 832 sub-buckets (<=1024)

    char* ws = (char*)d_ws;
    size_t o = 0;
    float* stats = (float*)(ws + o); o += 512;
    float* ss = (float*)(ws + o); o += 512;
    int* cnt2 = (int*)(ws + o); o += 4096;           // 832 ints used
    size_t zero_span = o;                            // zero stats,ss,cnt2 only
    int* sbase = (int*)(ws + o); o += 3584;          // SUBTOT+1 ints
    int* scur = (int*)(ws + o); o += 3584;
    int* bcur13 = (int*)(ws + o); o += 64;
    int* deg = (int*)(ws + o); o += (size_t)4 * N;
    int* offs = (int*)(ws + o); o += (size_t)4 * N;
    float* dinv = (float*)(ws + o); o += (size_t)4 * N;
    unsigned short* xb = (unsigned short*)(ws + o); o += (size_t)128 * N;
    unsigned* aggb32 = (unsigned*)(ws + o); o += (size_t)128 * N;
    unsigned* binned = (unsigned*)(ws + o); o += (size_t)4 * E;
    unsigned* sorted2 = (unsigned*)(ws + o); o += (size_t)4 * E;
    int* csr = (int*)binned;  // alias: binned consumed by k_sub before k_csr

    hipMemsetAsync(stats, 0, zero_span, stream);

    int n4 = N * 16;
    int preBlocks = ((n4 + 255) / 256 > (E + 4095) / 4096) ? (n4 + 255) / 256
                                                           : (E + 4095) / 4096;
    k_pre<<<preBlocks, 256, 0, stream>>>(x, dst, xb, cnt2, E, n4, SUBTOT);
    k_scanSub<<<1, 1024, 0, stream>>>(cnt2, sbase, scur, bcur13, SUBTOT, E);
    k_bin<<<(E + 4095) / 4096, 256, 0, stream>>>(src, dst, bcur13, binned, E);
    k_sub<<<B * 32, 256, 0, stream>>>(binned, sbase, scur, sorted2, B);
    k_csr<<<SUBTOT, 256, 0, stream>>>(sorted2, sbase, deg, dinv, offs, csr, N);
    k_agg<<<2048, 256, 0, stream>>>(offs, deg, csr, xb, dinv, aggb32, N);
    k_gemm1<<<NB, 256, 0, stream>>>(aggb32, W, stats, N);
    k_bnprep<<<1, 64, 0, stream>>>(stats, gamma, beta, ss, 1.0f / (float)N);
    k_gemm2<<<NB, 256, 0, stream>>>(aggb32, W, ss, out, N);
}

// Round 11
// 253.044 us; speedup vs baseline: 1.7723x; 1.0347x over previous
//
#include <hip/hip_runtime.h>
#include <hip/hip_bf16.h>

#ifndef BN_EPS
#define BN_EPS 1e-5f
#endif

// ---------------------------------------------------------------------------
// N=100000, C=64, E=1600000.
// R11: dispatch-count reduction (R10 analysis: ~100us of the 262 is spread
// across 11 dispatch overheads/tails, k_agg itself is at its fetch floor).
//   - coarse binning fused into k_pre (R7 retry, overflow actually fixed:
//     cap = E/12 + 16384 = mean + 53 sigma; R7's was mean + 0.5 sigma).
//   - bnprep folded into k_gemm2 prologue; stats zeroed in k_scanSub.
//   - 8 dispatches: memset, pre(bin), scanSub, sub, csr, agg, gemm1, gemm2.
// k_agg left as-is: FETCH 166MB ~= logical random-gather floor at 3.4 TB/s;
// fp8 would halve it but est. absmax ~0.5 > 0.105 threshold.
// bias cancels inside BatchNorm, skipped.
// ---------------------------------------------------------------------------

#define NPB 8192
#define NPB_SHIFT 13

__device__ __forceinline__ unsigned short f2bf(float f) {
    unsigned u = __float_as_uint(f);
    u += 0x7FFF + ((u >> 16) & 1);  // round-to-nearest-even
    return (unsigned short)(u >> 16);
}
__device__ __forceinline__ float bf2f(unsigned v) {
    return __uint_as_float(v << 16);
}

// Fused: coarse 13-bucket LDS chunk-sort (slack-capacity regions, cursor in
// bcnt) + 832-subbucket histogram (cnt2) + x->bf16.
__global__ __launch_bounds__(256) void k_pre(const float* __restrict__ x,
                                             const int* __restrict__ src,
                                             const int* __restrict__ dst,
                                             unsigned short* __restrict__ xb,
                                             int* __restrict__ cnt2,
                                             int* __restrict__ bcnt,
                                             unsigned* __restrict__ binned,
                                             int E, int n4, int SUBTOT, int cap) {
    __shared__ int hist[16], hexcl[16], hcur[16], gbase[16];
    __shared__ int h2[1024];
    __shared__ unsigned lout[4096];
    __shared__ unsigned char lb[4096];
    int tid = threadIdx.x;
    int c0 = blockIdx.x * 4096;
    if (c0 < E) {  // block-uniform branch
        int cnt = min(4096, E - c0);
        if (tid < 16) hist[tid] = 0;
        for (int i = tid; i < SUBTOT; i += 256) h2[i] = 0;
        __syncthreads();
        for (int i = tid; i < cnt; i += 256) {
            int d = dst[c0 + i];
            atomicAdd(&hist[d >> NPB_SHIFT], 1);
            atomicAdd(&h2[d >> 7], 1);
        }
        __syncthreads();
        if (tid == 0) {
            int acc = 0;
            for (int b = 0; b < 16; b++) { hexcl[b] = acc; hcur[b] = acc; acc += hist[b]; }
        }
        __syncthreads();
        if (tid < 16 && hist[tid] > 0) gbase[tid] = atomicAdd(&bcnt[tid], hist[tid]);
        for (int i = tid; i < SUBTOT; i += 256) {
            int v = h2[i];
            if (v > 0) atomicAdd(&cnt2[i], v);
        }
        for (int i = tid; i < cnt; i += 256) {
            int d = dst[c0 + i];
            int s = src[c0 + i];
            int b = d >> NPB_SHIFT;
            unsigned packed = (unsigned)s | ((unsigned)(d & (NPB - 1)) << 17);
            int p = atomicAdd(&hcur[b], 1);
            lout[p] = packed;
            lb[p] = (unsigned char)b;
        }
        __syncthreads();
        for (int i = tid; i < cnt; i += 256) {
            int b = lb[i];
            binned[(size_t)b * cap + gbase[b] + (i - hexcl[b])] = lout[i];
        }
    }
    int i = blockIdx.x * 256 + tid;
    if (i < n4) {
        float4 v = ((const float4*)x)[i];
        ushort4 b;
        b.x = f2bf(v.x); b.y = f2bf(v.y); b.z = f2bf(v.z); b.w = f2bf(v.w);
        ((ushort4*)xb)[i] = b;
    }
}

// Exact scan of cnt2 -> sbase (excl, +sentinel), scur copy; also zeroes stats.
__global__ __launch_bounds__(1024) void k_scanSub(const int* __restrict__ cnt2,
                                                  int* __restrict__ sbase,
                                                  int* __restrict__ scur,
                                                  float* __restrict__ stats,
                                                  int SUBTOT, int E) {
    __shared__ int s[1024];
    int t = threadIdx.x;
    if (t < 128) stats[t] = 0.f;
    int v = (t < SUBTOT) ? cnt2[t] : 0;
    s[t] = v;
    __syncthreads();
    for (int off = 1; off < 1024; off <<= 1) {
        int add = (t >= off) ? s[t - off] : 0;
        __syncthreads();
        s[t] += add;
        __syncthreads();
    }
    if (t < SUBTOT) {
        int excl = s[t] - v;
        sbase[t] = excl;
        scur[t] = excl;
    }
    if (t == 0) sbase[SUBTOT] = E;
}

// Per coarse bucket (32 blocks each): chunk-sort into 64 sub-buckets at exact
// scur offsets. in: binned region [b*cap, b*cap+total). out: src | local7<<17.
__global__ __launch_bounds__(256) void k_sub(const unsigned* __restrict__ binned,
                                             const int* __restrict__ sbase,
                                             int* __restrict__ scur,
                                             unsigned* __restrict__ sorted2,
                                             int cap, int B) {
    __shared__ int hist[64], hexcl[64], hcur[64], gbase[64];
    __shared__ unsigned lout[4096];
    __shared__ unsigned char lb[4096];
    int b = blockIdx.x >> 5;
    int r = blockIdx.x & 31;
    if (b >= B) return;
    int tid = threadIdx.x;
    int total = sbase[(b + 1) << 6] - sbase[b << 6];
    const unsigned* bb = binned + (size_t)b * cap;
    for (int c0 = r * 4096; c0 < total; c0 += 32 * 4096) {
        int cnt = min(4096, total - c0);
        if (tid < 64) hist[tid] = 0;
        __syncthreads();
        for (int i = tid; i < cnt; i += 256)
            atomicAdd(&hist[(bb[c0 + i] >> 24) & 63], 1);  // local13>>7
        __syncthreads();
        if (tid == 0) {
            int acc = 0;
            for (int f = 0; f < 64; f++) { hexcl[f] = acc; hcur[f] = acc; acc += hist[f]; }
        }
        __syncthreads();
        if (tid < 64 && hist[tid] > 0)
            gbase[tid] = atomicAdd(&scur[(b << 6) + tid], hist[tid]);
        for (int i = tid; i < cnt; i += 256) {
            unsigned e = bb[c0 + i];
            int f = (e >> 24) & 63;
            unsigned rp = (e & 0x1FFFFu) | (((e >> 17) & 127u) << 17);
            int p = atomicAdd(&hcur[f], 1);
            lout[p] = rp;
            lb[p] = (unsigned char)f;
        }
        __syncthreads();
        for (int i = tid; i < cnt; i += 256) {
            int f = lb[i];
            sorted2[gbase[f] + (i - hexcl[f])] = lout[i];
        }
        __syncthreads();
    }
}

// One block per 128-node sub-bucket: private csr window scatter (single CU ->
// L2 merges) + deg/dinv/offs from the LDS histogram (coalesced 512B stores).
__global__ __launch_bounds__(256) void k_csr(const unsigned* __restrict__ sorted2,
                                             const int* __restrict__ sbase,
                                             int* __restrict__ deg,
                                             float* __restrict__ dinv,
                                             int* __restrict__ offs,
                                             int* __restrict__ csr, int N) {
    __shared__ int hist[128], lbase[128], lcur[128];
    int s = blockIdx.x;
    int j0 = sbase[s], j1 = sbase[s + 1];
    int tid = threadIdx.x;
    if (tid < 128) { hist[tid] = 0; lcur[tid] = 0; }
    __syncthreads();
    for (int j = j0 + tid; j < j1; j += 256)
        atomicAdd(&hist[sorted2[j] >> 17], 1);
    __syncthreads();
    if (tid == 0) {
        int acc = 0;
        for (int k = 0; k < 128; k++) { lbase[k] = acc; acc += hist[k]; }
    }
    __syncthreads();
    if (tid < 128) {  // deg / dinv / offs for this sub-bucket's 128 nodes
        int n = (s << 7) + tid;
        if (n < N) {
            int d = hist[tid];
            deg[n] = d;
            dinv[n] = rsqrtf((float)(d + 1));  // +1 = self-loop
            offs[n] = j0 + lbase[tid];         // csr is globally dst-ordered
        }
    }
    for (int j = j0 + tid; j < j1; j += 256) {
        unsigned e = sorted2[j];
        int ld = e >> 17;
        int pos = j0 + lbase[ld] + atomicAdd(&lcur[ld], 1);
        csr[pos] = (int)(e & 0x1FFFFu);
    }
}

// Wave per node. lane = (half h, channel-pair p): one 4B load = 2 channels of
// one of 2 edges -> 2 edges per load instruction. Halves combined at the end.
__global__ __launch_bounds__(256) void k_agg(const int* __restrict__ offs,
                                             const int* __restrict__ deg,
                                             const int* __restrict__ csr,
                                             const unsigned short* __restrict__ xb,
                                             const float* __restrict__ dinv,
                                             unsigned* __restrict__ aggb32, int N) {
    int lane = threadIdx.x & 63;
    int p = lane & 31;   // channel pair (channels 2p, 2p+1)
    int h = lane >> 5;   // half: which edge of a pair this lane gathers
    int wid = (blockIdx.x * 256 + threadIdx.x) >> 6;
    int nw = (gridDim.x * 256) >> 6;

    for (int n = wid; n < N; n += nw) {
        float dn = dinv[n];
        unsigned sv = *(const unsigned*)(xb + (size_t)n * 64 + 2 * p);
        float wself = (h == 0) ? dn : 0.f;  // self-loop counted once
        float accx = bf2f(sv & 0xFFFFu) * wself;
        float accy = bf2f(sv >> 16) * wself;
        int j0 = offs[n];
        int j1 = j0 + deg[n];
        for (int jb = j0; jb < j1; jb += 64) {
            int cnt = min(64, j1 - jb);
            int idx = 0;
            float w = 0.f;
            if (lane < cnt) {
                idx = csr[jb + lane];
                w = dinv[idx];
            }
            int j = 0;
            for (; j + 8 <= cnt; j += 8) {
                int s0 = __shfl(idx, j + 0 + h), s1 = __shfl(idx, j + 2 + h);
                int s2 = __shfl(idx, j + 4 + h), s3 = __shfl(idx, j + 6 + h);
                float w0 = __shfl(w, j + 0 + h), w1 = __shfl(w, j + 2 + h);
                float w2 = __shfl(w, j + 4 + h), w3 = __shfl(w, j + 6 + h);
                unsigned v0 = *(const unsigned*)(xb + (size_t)s0 * 64 + 2 * p);
                unsigned v1 = *(const unsigned*)(xb + (size_t)s1 * 64 + 2 * p);
                unsigned v2 = *(const unsigned*)(xb + (size_t)s2 * 64 + 2 * p);
                unsigned v3 = *(const unsigned*)(xb + (size_t)s3 * 64 + 2 * p);
                accx = fmaf(w0, bf2f(v0 & 0xFFFFu), accx);
                accy = fmaf(w0, bf2f(v0 >> 16), accy);
                accx = fmaf(w1, bf2f(v1 & 0xFFFFu), accx);
                accy = fmaf(w1, bf2f(v1 >> 16), accy);
                accx = fmaf(w2, bf2f(v2 & 0xFFFFu), accx);
                accy = fmaf(w2, bf2f(v2 >> 16), accy);
                accx = fmaf(w3, bf2f(v3 & 0xFFFFu), accx);
                accy = fmaf(w3, bf2f(v3 >> 16), accy);
            }
            for (; j + 2 <= cnt; j += 2) {
                int s0 = __shfl(idx, j + h);
                float w0 = __shfl(w, j + h);
                unsigned v0 = *(const unsigned*)(xb + (size_t)s0 * 64 + 2 * p);
                accx = fmaf(w0, bf2f(v0 & 0xFFFFu), accx);
                accy = fmaf(w0, bf2f(v0 >> 16), accy);
            }
            if (j < cnt) {  // odd tail: half 0 contributes, half 1 gets w=0
                int s0 = __shfl(idx, j);
                float w0 = __shfl(w, j);
                if (h) w0 = 0.f;
                unsigned v0 = *(const unsigned*)(xb + (size_t)s0 * 64 + 2 * p);
                accx = fmaf(w0, bf2f(v0 & 0xFFFFu), accx);
                accy = fmaf(w0, bf2f(v0 >> 16), accy);
            }
        }
        accx += __shfl_xor(accx, 32);
        accy += __shfl_xor(accy, 32);
        if (h == 0) {
            unsigned o = (unsigned)f2bf(accx * dn) | ((unsigned)f2bf(accy * dn) << 16);
            aggb32[(size_t)n * 32 + p] = o;
        }
    }
}

// Stats pass: o = agg@W per row (same structure as k_gemm2, NO stores).
// lane=channel -> psum/psq in registers; LDS-reduce across 4 waves; 128
// atomics per block total.
__global__ __launch_bounds__(256) void k_gemm1(const unsigned* __restrict__ aggb32,
                                               const float* __restrict__ W,
                                               float* __restrict__ stats, int N) {
    __shared__ unsigned tile[256 * 32];
    __shared__ float red[512];  // [2][4][64]
    int t = threadIdx.x;
    int lane = t & 63;
    int w = t >> 6;
    int r0 = blockIdx.x * 256;
    const uint4* gp = (const uint4*)(aggb32 + (size_t)r0 * 32);
#pragma unroll
    for (int i = 0; i < 8; i++) {
        int idx = t + 256 * i;
        int n = r0 + (idx >> 3);
        uint4 v = {0u, 0u, 0u, 0u};
        if (n < N) v = gp[idx];
        *(uint4*)(tile + idx * 4) = v;
    }
    float wcol[64];
#pragma unroll
    for (int k = 0; k < 64; k++) wcol[k] = W[k * 64 + lane];
    __syncthreads();

    float psum = 0.f, psq = 0.f;
    for (int rr = 0; rr < 64; rr += 2) {
        int lr0 = w * 64 + rr;
        int n0 = r0 + lr0;
        if (n0 >= N) break;
        const unsigned* row0 = tile + lr0 * 32;
        const unsigned* row1 = row0 + 32;
        float o0 = 0.f, o1 = 0.f;
#pragma unroll
        for (int kp = 0; kp < 32; kp++) {
            unsigned u0 = row0[kp], u1 = row1[kp];
            o0 = fmaf(bf2f(u0 & 0xFFFFu), wcol[2 * kp], o0);
            o0 = fmaf(bf2f(u0 >> 16), wcol[2 * kp + 1], o0);
            o1 = fmaf(bf2f(u1 & 0xFFFFu), wcol[2 * kp], o1);
            o1 = fmaf(bf2f(u1 >> 16), wcol[2 * kp + 1], o1);
        }
        psum += o0;
        psq = fmaf(o0, o0, psq);
        if (n0 + 1 < N) {
            psum += o1;
            psq = fmaf(o1, o1, psq);
        }
    }
    red[w * 64 + lane] = psum;
    red[256 + w * 64 + lane] = psq;
    __syncthreads();
    if (w == 0) {
        float s = red[lane] + red[64 + lane] + red[128 + lane] + red[192 + lane];
        atomicAdd(&stats[lane], s);
    } else if (w == 1) {
        float q = red[256 + lane] + red[320 + lane] + red[384 + lane] + red[448 + lane];
        atomicAdd(&stats[64 + lane], q);
    }
}

// out = BN(agg@W)+ReLU, BN scale/shift derived in-prologue from stats (bnprep
// folded in). lane=channel; agg rows staged in LDS; store = 1 dword/lane =
// 256B contiguous per row (full lines, no amplification).
__global__ __launch_bounds__(256) void k_gemm2(const unsigned* __restrict__ aggb32,
                                               const float* __restrict__ W,
                                               const float* __restrict__ stats,
                                               const float* __restrict__ gamma,
                                               const float* __restrict__ beta,
                                               float* __restrict__ out, int N,
                                               float invN) {
    __shared__ unsigned tile[256 * 32];
    __shared__ float ssl[128];
    int t = threadIdx.x;
    int lane = t & 63;
    int w = t >> 6;
    int r0 = blockIdx.x * 256;
    const uint4* gp = (const uint4*)(aggb32 + (size_t)r0 * 32);
#pragma unroll
    for (int i = 0; i < 8; i++) {
        int idx = t + 256 * i;
        int n = r0 + (idx >> 3);
        uint4 v = {0u, 0u, 0u, 0u};
        if (n < N) v = gp[idx];
        *(uint4*)(tile + idx * 4) = v;
    }
    if (t < 64) {  // bnprep folded in (redundant per block, trivial)
        float mean = stats[t] * invN;
        float var = stats[64 + t] * invN - mean * mean;  // biased var
        float sc = gamma[t] * rsqrtf(var + BN_EPS);
        ssl[t] = sc;
        ssl[64 + t] = beta[t] - mean * sc;
    }
    float wcol[64];
#pragma unroll
    for (int k = 0; k < 64; k++) wcol[k] = W[k * 64 + lane];
    __syncthreads();
    float sc = ssl[lane], sh = ssl[64 + lane];

    for (int rr = 0; rr < 64; rr += 2) {
        int lr0 = w * 64 + rr;
        int n0 = r0 + lr0;
        if (n0 >= N) break;
        const unsigned* row0 = tile + lr0 * 32;
        const unsigned* row1 = row0 + 32;
        float o0 = 0.f, o1 = 0.f;
#pragma unroll
        for (int kp = 0; kp < 32; kp++) {
            unsigned u0 = row0[kp], u1 = row1[kp];
            o0 = fmaf(bf2f(u0 & 0xFFFFu), wcol[2 * kp], o0);
            o0 = fmaf(bf2f(u0 >> 16), wcol[2 * kp + 1], o0);
            o1 = fmaf(bf2f(u1 & 0xFFFFu), wcol[2 * kp], o1);
            o1 = fmaf(bf2f(u1 >> 16), wcol[2 * kp + 1], o1);
        }
        o0 = fmaxf(fmaf(o0, sc, sh), 0.f);
        o1 = fmaxf(fmaf(o1, sc, sh), 0.f);
        out[(size_t)n0 * 64 + lane] = o0;
        if (n0 + 1 < N) out[(size_t)(n0 + 1) * 64 + lane] = o1;
    }
}

extern "C" void kernel_launch(void* const* d_in, const int* in_sizes, int n_in,
                              void* d_out, int out_size, void* d_ws, size_t ws_size,
                              hipStream_t stream) {
    const float* x = (const float*)d_in[0];
    const int* ei = (const int*)d_in[1];
    const float* W = (const float*)d_in[2];
    // d_in[3] = bias: cancels inside BatchNorm, unused.
    const float* gamma = (const float*)d_in[4];
    const float* beta = (const float*)d_in[5];
    float* out = (float*)d_out;

    const int N = in_sizes[0] / 64;
    const int E = in_sizes[1] / 2;
    const int* src = ei;
    const int* dst = ei + E;
    const int NB = (N + 255) / 256;             // 391
    const int B = (N + NPB - 1) >> NPB_SHIFT;   // 13 coarse buckets
    const int SUBTOT = B * 64;                  // 832 sub-buckets (<=1024)
    // Slack capacity per coarse bucket: mean bucket count is E*8192/N ~= 131K,
    // sigma ~= 350. E/12 + 16384 ~= mean + 53 sigma -> overflow impossible.
    const int cap = E / 12 + 16384;

    char* ws = (char*)d_ws;
    size_t o = 0;
    float* stats = (float*)(ws + o); o += 512;       // zeroed in k_scanSub
    int* cnt2 = (int*)(ws + o); o += 4096;           // 832 ints used
    int* bcnt = (int*)(ws + o); o += 64;             // 13 coarse cursors
    size_t z0 = 512, z1 = 4096 + 64;                 // memset covers cnt2+bcnt
    int* sbase = (int*)(ws + o); o += 3584;          // SUBTOT+1 ints
    int* scur = (int*)(ws + o); o += 3584;
    int* deg = (int*)(ws + o); o += (size_t)4 * N;
    int* offs = (int*)(ws + o); o += (size_t)4 * N;
    float* dinv = (float*)(ws + o); o += (size_t)4 * N;
    unsigned short* xb = (unsigned short*)(ws + o); o += (size_t)128 * N;
    unsigned* aggb32 = (unsigned*)(ws + o); o += (size_t)128 * N;
    unsigned* binned = (unsigned*)(ws + o); o += (size_t)4 * B * cap;
    unsigned* sorted2 = (unsigned*)(ws + o); o += (size_t)4 * E;
    int* csr = (int*)binned;  // alias: binned consumed by k_sub before k_csr

    hipMemsetAsync(ws + z0, 0, z1, stream);

    int n4 = N * 16;
    int preBlocks = ((n4 + 255) / 256 > (E + 4095) / 4096) ? (n4 + 255) / 256
                                                           : (E + 4095) / 4096;
    k_pre<<<preBlocks, 256, 0, stream>>>(x, src, dst, xb, cnt2, bcnt, binned,
                                         E, n4, SUBTOT, cap);
    k_scanSub<<<1, 1024, 0, stream>>>(cnt2, sbase, scur, stats, SUBTOT, E);
    k_sub<<<B * 32, 256, 0, stream>>>(binned, sbase, scur, sorted2, cap, B);
    k_csr<<<SUBTOT, 256, 0, stream>>>(sorted2, sbase, deg, dinv, offs, csr, N);
    k_agg<<<2048, 256, 0, stream>>>(offs, deg, csr, xb, dinv, aggb32, N);
    k_gemm1<<<NB, 256, 0, stream>>>(aggb32, W, stats, N);
    k_gemm2<<<NB, 256, 0, stream>>>(aggb32, W, stats, gamma, beta, out, N,
                                    1.0f / (float)N);
}